// Round 6
// baseline (692.067 us; speedup 1.0000x reference)
//
#include <hip/hip_runtime.h>
#include <hip/hip_cooperative_groups.h>
#include <hip/hip_bf16.h>
#include <math.h>

namespace cg = cooperative_groups;

#define NEG_SLOPE 0.2f

constexpr int D = 256;       // hid width (all attention stages use D=256)
constexpr int HEADS = 4;
constexpr int MAXB = 128;    // fixed bucket stride; deg ~ Poisson(32), P(>128) ~ 0

typedef __attribute__((ext_vector_type(8))) short short8;   // bf16x8 MFMA frag (4 VGPR)
typedef __attribute__((ext_vector_type(4))) float floatx4;  // fp32 accumulator

// ---------------- bf16 split helpers: v ~= hi + lo, rel err ~2^-16 ----------------
__device__ inline unsigned short bf16_hi_trunc(float v) {
  return (unsigned short)(__float_as_uint(v) >> 16);
}
__device__ inline float bf16_tof(unsigned short u) {
  return __uint_as_float(((unsigned int)u) << 16);
}
__device__ inline unsigned short bf16_rn(float v) {
  unsigned int b = __float_as_uint(v);
  b += 0x7fffu + ((b >> 16) & 1u);
  return (unsigned short)(b >> 16);
}
__device__ inline void split2(float v, unsigned short& hi, unsigned short& lo) {
  hi = bf16_hi_trunc(v);
  lo = bf16_rn(v - bf16_tof(hi));
}

// =================== device-side phase bodies (shared by mega + fallback) ===================

// ---- prep: zeroing + x split + all weight transposes (3536 work units) ----
__device__ __forceinline__ void prep_body(
    int* __restrict__ zeroBase, int zeroN,
    const float* __restrict__ x, unsigned short* __restrict__ xhi, unsigned short* __restrict__ xlo,
    int xN4,
    const float* __restrict__ l0hW, unsigned short* __restrict__ l0hHi, unsigned short* __restrict__ l0hLo,
    const float* __restrict__ l1hW, unsigned short* __restrict__ l1hHi, unsigned short* __restrict__ l1hLo,
    const float* __restrict__ l0oW, unsigned short* __restrict__ l0oHi, unsigned short* __restrict__ l0oLo,
    const float* __restrict__ l1oW, unsigned short* __restrict__ l1oHi, unsigned short* __restrict__ l1oLo,
    const float* __restrict__ linW, unsigned short* __restrict__ linHi, unsigned short* __restrict__ linLo,
    float* __restrict__ tileF /* >= 32*33 floats of LDS */) {
  const int t = threadIdx.x;
  for (int b = blockIdx.x; b < 3536; b += gridDim.x) {
    if (b < 528) {
      int idx = b * 256 + t;
      if (idx < zeroN) zeroBase[idx] = 0;
      continue;
    }
    if (b < 2576) {
      int idx = (b - 528) * 256 + t;
      if (idx < xN4) {
        float4 v = ((const float4*)x)[idx];
        ushort4 h, l;
        split2(v.x, h.x, l.x);
        split2(v.y, h.y, l.y);
        split2(v.z, h.z, l.z);
        split2(v.w, h.w, l.w);
        ((ushort4*)xhi)[idx] = h;
        ((ushort4*)xlo)[idx] = l;
      }
      continue;
    }
    __syncthreads();   // WAR guard on tileF across grid-stride iterations (b uniform per block)
    const int tr = t >> 5, tc = t & 31;
    if (b < 3088) {                       // l0_hW: K=512, N=256, 4 heads
      const int bi = b - 2576;
      const int kb = bi & 15;
      const int nb = (bi >> 4) & 7;
      const int h = bi >> 7;
      const int K = 512, N = 256;
      const int k0 = kb * 32, n0 = nb * 32;
      const float* B = l0hW + (size_t)h * K * N;
#pragma unroll
      for (int i = 0; i < 4; ++i)
        tileF[(tr + 8 * i) * 33 + tc] = B[(size_t)(k0 + tr + 8 * i) * N + (n0 + tc)];
      __syncthreads();
      unsigned short* Thi = l0hHi + (size_t)h * N * K;
      unsigned short* Tlo = l0hLo + (size_t)h * N * K;
#pragma unroll
      for (int i = 0; i < 4; ++i) {
        int n = n0 + tr + 8 * i, k = k0 + tc;
        float v = tileF[tc * 33 + tr + 8 * i];
        unsigned short hi, lo;
        split2(v, hi, lo);
        Thi[(size_t)n * K + k] = hi;
        Tlo[(size_t)n * K + k] = lo;
      }
      continue;
    }
    // 7-slice section (all K=256)
    const int bi = b - 3088;
    const int kb = bi & 7;
    const int nb = (bi >> 3) & 7;
    const int z = bi >> 6;
    const int K = 256;
    const int N = (z == 6) ? 128 : 256;
    const int k0 = kb * 32, n0 = nb * 32;
    if (n0 >= N) continue;               // uniform per block
    const float* B;
    unsigned short *Thi, *Tlo;
    if (z < 4) {
      B = l1hW + (size_t)z * K * 256;
      Thi = l1hHi + (size_t)z * 256 * K;
      Tlo = l1hLo + (size_t)z * 256 * K;
    } else if (z == 4) { B = l0oW; Thi = l0oHi; Tlo = l0oLo; }
    else if (z == 5)   { B = l1oW; Thi = l1oHi; Tlo = l1oLo; }
    else               { B = linW; Thi = linHi; Tlo = linLo; }
#pragma unroll
    for (int i = 0; i < 4; ++i)
      tileF[(tr + 8 * i) * 33 + tc] = B[(size_t)(k0 + tr + 8 * i) * N + (n0 + tc)];
    __syncthreads();
#pragma unroll
    for (int i = 0; i < 4; ++i) {
      int n = n0 + tr + 8 * i, k = k0 + tc;
      float v = tileF[tc * 33 + tr + 8 * i];
      unsigned short hi, lo;
      split2(v, hi, lo);
      Thi[(size_t)n * K + k] = hi;
      Tlo[(size_t)n * K + k] = lo;
    }
  }
}

// ---- bucketed CSR fill ----
__device__ __forceinline__ void fill_body(const int* __restrict__ src, const int* __restrict__ dst,
                                          int* __restrict__ cnt, int* __restrict__ colb, int E) {
  for (int k = blockIdx.x * 256 + threadIdx.x; k < E; k += gridDim.x * 256) {
    int s = src[k];
    int pos = atomicAdd(&cnt[s], 1);
    if (pos < MAXB) colb[s * MAXB + pos] = dst[k];
  }
}

// ---- dedupe: 2 rows per 256-thread block ----
__device__ __forceinline__ void dedupe_body(const int* __restrict__ cnt, int* __restrict__ colb,
                                            int Nn, int* __restrict__ cs /* 256 ints LDS */) {
  const int sub = threadIdx.x >> 7;        // 0/1
  const int t7 = threadIdx.x & 127;
  for (int u = blockIdx.x; u < (Nn >> 1); u += gridDim.x) {
    __syncthreads();                       // WAR guard on cs across iterations
    const int i = (u << 1) + sub;
    int len = cnt[i];
    if (len > MAXB) len = MAXB;
    if (t7 < len) cs[(sub << 7) + t7] = colb[i * MAXB + t7];
    __syncthreads();
    if (t7 < len) {
      int c = cs[(sub << 7) + t7];
      bool dup = false;
      for (int s2 = 0; s2 < t7; ++s2)
        if (cs[(sub << 7) + s2] == c) { dup = true; break; }
      if (dup) colb[i * MAXB + t7] = -1;
    }
  }
}

// ---- split-bf16 MFMA GEMM, 64x64 tile, R15 pipelined body, grid-stride over tiles ----
// Output: Cb != nullptr -> bf16-rn [row][Htot][N]; else fp32 C [row][N].
// aptr != nullptr: fused alphabeta epilogue, alphaB/betaB laid [row][Htot] (pre-zeroed).
__device__ __forceinline__ void gemm_body(
    const unsigned short* __restrict__ Ahi, const unsigned short* __restrict__ Alo,
    const unsigned short* __restrict__ Bthi, const unsigned short* __restrict__ Btlo,
    const float* __restrict__ bias, float* __restrict__ C, unsigned short* __restrict__ Cb,
    const float* __restrict__ aptr, float* __restrict__ alphaB, float* __restrict__ betaB,
    int N, int K, int Htot, int tilesX, int tilesTotal,
    unsigned short* __restrict__ sA0, unsigned short* __restrict__ sA1,
    unsigned short* __restrict__ sB0, unsigned short* __restrict__ sB1) {
  constexpr int LSTR = 72;
  const int tid = threadIdx.x;
  const int lane = tid & 63;
  const int wv = tid >> 6;
  const int wm = (wv & 1) * 32;
  const int wn = (wv >> 1) * 32;
  const int q = lane >> 4;
  const int l15 = lane & 15;
  const size_t rowStride = (size_t)Htot * N;

  for (int tt = blockIdx.x; tt < tilesTotal; tt += gridDim.x) {
    const int bm = (tt % tilesX) << 6;
    const int gn = (tt / tilesX) << 6;
    const int head = gn / N;
    const int bn = gn - head * N;

    floatx4 acc[2][2];
#pragma unroll
    for (int i = 0; i < 2; ++i)
#pragma unroll
      for (int j = 0; j < 2; ++j) acc[i][j] = (floatx4)0.0f;

    short8 ra[2][2], rb[2][2];
#pragma unroll
    for (int i = 0; i < 2; ++i) {   // prologue: tile 0
      const int c = tid + 256 * i;
      const int row = c >> 3, koff = (c & 7) << 3;
      rb[0][i] = *(const short8*)(Bthi + (size_t)(gn + row) * K + koff);
      rb[1][i] = *(const short8*)(Btlo + (size_t)(gn + row) * K + koff);
      ra[0][i] = *(const short8*)(Ahi + (size_t)(bm + row) * K + koff);
      ra[1][i] = *(const short8*)(Alo + (size_t)(bm + row) * K + koff);
    }

    for (int k0 = 0; k0 < K; k0 += 64) {
      __builtin_amdgcn_s_barrier();      // barrier A: prev LDS reads consumed
      __builtin_amdgcn_sched_barrier(0);
#pragma unroll
      for (int i = 0; i < 2; ++i) {
        const int c = tid + 256 * i;
        const int row = c >> 3, koff = (c & 7) << 3;
        *(short8*)(&sA0[row * LSTR + koff]) = ra[0][i];
        *(short8*)(&sA1[row * LSTR + koff]) = ra[1][i];
        *(short8*)(&sB0[row * LSTR + koff]) = rb[0][i];
        *(short8*)(&sB1[row * LSTR + koff]) = rb[1][i];
      }
      if (k0 + 64 < K) {   // next-tile loads stay in flight across barrier B
#pragma unroll
        for (int i = 0; i < 2; ++i) {
          const int c = tid + 256 * i;
          const int row = c >> 3, koff = (c & 7) << 3;
          const size_t boff = (size_t)(gn + row) * K + k0 + 64 + koff;
          rb[0][i] = *(const short8*)(Bthi + boff);
          rb[1][i] = *(const short8*)(Btlo + boff);
          const size_t aoff = (size_t)(bm + row) * K + k0 + 64 + koff;
          ra[0][i] = *(const short8*)(Ahi + aoff);
          ra[1][i] = *(const short8*)(Alo + aoff);
        }
      }
      asm volatile("s_waitcnt lgkmcnt(0)" ::: "memory");   // publish ds_writes (no vmcnt drain)
      __builtin_amdgcn_sched_barrier(0);
      __builtin_amdgcn_s_barrier();
      __builtin_amdgcn_sched_barrier(0);
#pragma unroll
      for (int kc = 0; kc < 2; ++kc) {
        const int ko = kc * 32 + q * 8;
        short8 aH[2], aL[2], bH[2], bL[2];
#pragma unroll
        for (int i = 0; i < 2; ++i) {
          aH[i] = *(const short8*)(&sA0[(wm + i * 16 + l15) * LSTR + ko]);
          aL[i] = *(const short8*)(&sA1[(wm + i * 16 + l15) * LSTR + ko]);
          bH[i] = *(const short8*)(&sB0[(wn + i * 16 + l15) * LSTR + ko]);
          bL[i] = *(const short8*)(&sB1[(wn + i * 16 + l15) * LSTR + ko]);
        }
#pragma unroll
        for (int i = 0; i < 2; ++i)
#pragma unroll
          for (int j = 0; j < 2; ++j) {
            acc[i][j] = __builtin_amdgcn_mfma_f32_16x16x32_bf16(aH[i], bH[j], acc[i][j], 0, 0, 0);
            acc[i][j] = __builtin_amdgcn_mfma_f32_16x16x32_bf16(aH[i], bL[j], acc[i][j], 0, 0, 0);
            acc[i][j] = __builtin_amdgcn_mfma_f32_16x16x32_bf16(aL[i], bH[j], acc[i][j], 0, 0, 0);
          }
      }
    }
    // epilogue: n = lane&15 (col), m = quad*4 + reg (row)
    const size_t headOff = (size_t)head * N;
    const int colh0 = bn + wn + l15;
    const int colh1 = colh0 + 16;
    const float bv0 = bias[head * N + colh0];
    const float bv1 = bias[head * N + colh1];
    float as0 = 0.f, as1 = 0.f, ad0 = 0.f, ad1 = 0.f;
    if (aptr) {
      as0 = aptr[head * 2 * N + colh0];
      as1 = aptr[head * 2 * N + colh1];
      ad0 = aptr[head * 2 * N + N + colh0];
      ad1 = aptr[head * 2 * N + N + colh1];
    }
#pragma unroll
    for (int i = 0; i < 2; ++i) {
      const int rowb = bm + wm + i * 16 + q * 4;
#pragma unroll
      for (int r = 0; r < 4; ++r) {
        const float o0 = acc[i][0][r] + bv0;
        const float o1 = acc[i][1][r] + bv1;
        if (Cb) {
          Cb[(size_t)(rowb + r) * rowStride + headOff + colh0] = bf16_rn(o0);
          Cb[(size_t)(rowb + r) * rowStride + headOff + colh1] = bf16_rn(o1);
        } else {
          C[(size_t)(rowb + r) * N + colh0] = o0;
          C[(size_t)(rowb + r) * N + colh1] = o1;
        }
        if (aptr) {  // wave-uniform; alpha/beta from fp32 acc (exact)
          float pa = o0 * as0 + o1 * as1;
          float pb = o0 * ad0 + o1 * ad1;
#pragma unroll
          for (int off = 1; off < 16; off <<= 1) {
            pa += __shfl_xor(pa, off, 64);
            pb += __shfl_xor(pb, off, 64);
          }
          if (l15 == 0) {
            atomicAdd(&alphaB[(size_t)(rowb + r) * Htot + head], pa);
            atomicAdd(&betaB[(size_t)(rowb + r) * Htot + head], pb);
          }
        }
      }
    }
  }
}

// ---- fused 4-head attention + ELU + head-mean (R13/R15 body, grid-stride) ----
__device__ __forceinline__ void attn4_body(
    const unsigned short* __restrict__ hB,
    const float* __restrict__ alpha, const float* __restrict__ beta,
    const float* __restrict__ ab, const int* __restrict__ cnt,
    const int* __restrict__ colb,
    unsigned short* __restrict__ oHi, unsigned short* __restrict__ oLo, int Nn) {
  const int tid = threadIdx.x;
  const int lane = tid & 63;
  const int wv = tid >> 6;
  const unsigned short* hL = hB + (lane << 2);
  const float ab0 = ab[0], ab1 = ab[1], ab2 = ab[2], ab3 = ab[3];

  for (int u = blockIdx.x; u < (Nn >> 2); u += gridDim.x) {
    const int i = u * 4 + wv;
    const float ai0 = alpha[i * HEADS + 0] + ab0;
    const float ai1 = alpha[i * HEADS + 1] + ab1;
    const float ai2 = alpha[i * HEADS + 2] + ab2;
    const float ai3 = alpha[i * HEADS + 3] + ab3;
    const int start = i * MAXB;
    int len = cnt[i];
    if (len > MAXB) len = MAXB;

    float m0 = -3.0e38f, m1 = -3.0e38f, m2 = -3.0e38f, m3 = -3.0e38f;
    float s0 = 0.f, s1 = 0.f, s2 = 0.f, s3 = 0.f;
    float4 A0 = make_float4(0.f, 0.f, 0.f, 0.f);
    float4 A1 = make_float4(0.f, 0.f, 0.f, 0.f);
    float4 A2 = make_float4(0.f, 0.f, 0.f, 0.f);
    float4 A3 = make_float4(0.f, 0.f, 0.f, 0.f);

    for (int t0 = 0; t0 < len; t0 += 64) {
      const int t = t0 + lane;
      const int c = (t < len) ? colb[start + t] : -1;
      float e0 = -3.0e38f, e1 = -3.0e38f, e2 = -3.0e38f, e3 = -3.0e38f;
      if (c >= 0) {
        const float4 b4 = *(const float4*)(beta + (size_t)c * HEADS);
        e0 = ai0 + b4.x; e1 = ai1 + b4.y; e2 = ai2 + b4.z; e3 = ai3 + b4.w;
        e0 = e0 > 0.0f ? e0 : NEG_SLOPE * e0;
        e1 = e1 > 0.0f ? e1 : NEG_SLOPE * e1;
        e2 = e2 > 0.0f ? e2 : NEG_SLOPE * e2;
        e3 = e3 > 0.0f ? e3 : NEG_SLOPE * e3;
      }
      float c0 = e0, c1 = e1, c2 = e2, c3 = e3;
#pragma unroll
      for (int off = 32; off > 0; off >>= 1) {
        c0 = fmaxf(c0, __shfl_xor(c0, off, 64));
        c1 = fmaxf(c1, __shfl_xor(c1, off, 64));
        c2 = fmaxf(c2, __shfl_xor(c2, off, 64));
        c3 = fmaxf(c3, __shfl_xor(c3, off, 64));
      }
      const float n0 = fmaxf(m0, c0), n1 = fmaxf(m1, c1);
      const float n2 = fmaxf(m2, c2), n3 = fmaxf(m3, c3);
      const float sc0 = __expf(m0 - n0), sc1 = __expf(m1 - n1);
      const float sc2 = __expf(m2 - n2), sc3 = __expf(m3 - n3);
      float w0 = 0.f, w1 = 0.f, w2 = 0.f, w3 = 0.f;
      if (c >= 0) {
        w0 = __expf(e0 - n0); w1 = __expf(e1 - n1);
        w2 = __expf(e2 - n2); w3 = __expf(e3 - n3);
      }
      float q0 = w0, q1 = w1, q2 = w2, q3 = w3;
#pragma unroll
      for (int off = 32; off > 0; off >>= 1) {
        q0 += __shfl_xor(q0, off, 64);
        q1 += __shfl_xor(q1, off, 64);
        q2 += __shfl_xor(q2, off, 64);
        q3 += __shfl_xor(q3, off, 64);
      }
      s0 = s0 * sc0 + q0; s1 = s1 * sc1 + q1;
      s2 = s2 * sc2 + q2; s3 = s3 * sc3 + q3;
      A0.x *= sc0; A0.y *= sc0; A0.z *= sc0; A0.w *= sc0;
      A1.x *= sc1; A1.y *= sc1; A1.z *= sc1; A1.w *= sc1;
      A2.x *= sc2; A2.y *= sc2; A2.z *= sc2; A2.w *= sc2;
      A3.x *= sc3; A3.y *= sc3; A3.z *= sc3; A3.w *= sc3;
      m0 = n0; m1 = n1; m2 = n2; m3 = n3;

      const int cS = (c >= 0) ? c : 0;
      const int cnt2 = min(64, len - t0);
      int j = 0;
      for (; j + 2 <= cnt2; j += 2) {
        const int ca = __shfl(cS, j);
        const int cb = __shfl(cS, j + 1);
        const float wa0 = __shfl(w0, j),     wa1 = __shfl(w1, j);
        const float wa2 = __shfl(w2, j),     wa3 = __shfl(w3, j);
        const float wb0 = __shfl(w0, j + 1), wb1 = __shfl(w1, j + 1);
        const float wb2 = __shfl(w2, j + 1), wb3 = __shfl(w3, j + 1);
        const unsigned short* pa = hL + (size_t)ca * (HEADS * D);
        const unsigned short* pb = hL + (size_t)cb * (HEADS * D);
        const ushort4 ua0 = *(const ushort4*)(pa);
        const ushort4 ua1 = *(const ushort4*)(pa + D);
        const ushort4 ua2 = *(const ushort4*)(pa + 2 * D);
        const ushort4 ua3 = *(const ushort4*)(pa + 3 * D);
        const ushort4 ub0 = *(const ushort4*)(pb);
        const ushort4 ub1 = *(const ushort4*)(pb + D);
        const ushort4 ub2 = *(const ushort4*)(pb + 2 * D);
        const ushort4 ub3 = *(const ushort4*)(pb + 3 * D);
        A0.x += wa0 * bf16_tof(ua0.x); A0.y += wa0 * bf16_tof(ua0.y);
        A0.z += wa0 * bf16_tof(ua0.z); A0.w += wa0 * bf16_tof(ua0.w);
        A1.x += wa1 * bf16_tof(ua1.x); A1.y += wa1 * bf16_tof(ua1.y);
        A1.z += wa1 * bf16_tof(ua1.z); A1.w += wa1 * bf16_tof(ua1.w);
        A2.x += wa2 * bf16_tof(ua2.x); A2.y += wa2 * bf16_tof(ua2.y);
        A2.z += wa2 * bf16_tof(ua2.z); A2.w += wa2 * bf16_tof(ua2.w);
        A3.x += wa3 * bf16_tof(ua3.x); A3.y += wa3 * bf16_tof(ua3.y);
        A3.z += wa3 * bf16_tof(ua3.z); A3.w += wa3 * bf16_tof(ua3.w);
        A0.x += wb0 * bf16_tof(ub0.x); A0.y += wb0 * bf16_tof(ub0.y);
        A0.z += wb0 * bf16_tof(ub0.z); A0.w += wb0 * bf16_tof(ub0.w);
        A1.x += wb1 * bf16_tof(ub1.x); A1.y += wb1 * bf16_tof(ub1.y);
        A1.z += wb1 * bf16_tof(ub1.z); A1.w += wb1 * bf16_tof(ub1.w);
        A2.x += wb2 * bf16_tof(ub2.x); A2.y += wb2 * bf16_tof(ub2.y);
        A2.z += wb2 * bf16_tof(ub2.z); A2.w += wb2 * bf16_tof(ub2.w);
        A3.x += wb3 * bf16_tof(ub3.x); A3.y += wb3 * bf16_tof(ub3.y);
        A3.z += wb3 * bf16_tof(ub3.z); A3.w += wb3 * bf16_tof(ub3.w);
      }
      for (; j < cnt2; ++j) {
        const int ca = __shfl(cS, j);
        const float wa0 = __shfl(w0, j), wa1 = __shfl(w1, j);
        const float wa2 = __shfl(w2, j), wa3 = __shfl(w3, j);
        const unsigned short* pa = hL + (size_t)ca * (HEADS * D);
        const ushort4 ua0 = *(const ushort4*)(pa);
        const ushort4 ua1 = *(const ushort4*)(pa + D);
        const ushort4 ua2 = *(const ushort4*)(pa + 2 * D);
        const ushort4 ua3 = *(const ushort4*)(pa + 3 * D);
        A0.x += wa0 * bf16_tof(ua0.x); A0.y += wa0 * bf16_tof(ua0.y);
        A0.z += wa0 * bf16_tof(ua0.z); A0.w += wa0 * bf16_tof(ua0.w);
        A1.x += wa1 * bf16_tof(ua1.x); A1.y += wa1 * bf16_tof(ua1.y);
        A1.z += wa1 * bf16_tof(ua1.z); A1.w += wa1 * bf16_tof(ua1.w);
        A2.x += wa2 * bf16_tof(ua2.x); A2.y += wa2 * bf16_tof(ua2.y);
        A2.z += wa2 * bf16_tof(ua2.z); A2.w += wa2 * bf16_tof(ua2.w);
        A3.x += wa3 * bf16_tof(ua3.x); A3.y += wa3 * bf16_tof(ua3.y);
        A3.z += wa3 * bf16_tof(ua3.z); A3.w += wa3 * bf16_tof(ua3.w);
      }
    }

    const float i0 = 1.0f / s0, i1 = 1.0f / s1, i2 = 1.0f / s2, i3 = 1.0f / s3;
    auto elu = [](float v) { return v > 0.0f ? v : expm1f(v); };
    float4 xm;
    xm.x = 0.25f * (elu(A0.x * i0) + elu(A1.x * i1) + elu(A2.x * i2) + elu(A3.x * i3));
    xm.y = 0.25f * (elu(A0.y * i0) + elu(A1.y * i1) + elu(A2.y * i2) + elu(A3.y * i3));
    xm.z = 0.25f * (elu(A0.z * i0) + elu(A1.z * i1) + elu(A2.z * i2) + elu(A3.z * i3));
    xm.w = 0.25f * (elu(A0.w * i0) + elu(A1.w * i1) + elu(A2.w * i2) + elu(A3.w * i3));
    ushort4 h4, l4;
    split2(xm.x, h4.x, l4.x);
    split2(xm.y, h4.y, l4.y);
    split2(xm.z, h4.z, l4.z);
    split2(xm.w, h4.w, l4.w);
    const size_t q4 = ((size_t)i * D >> 2) + lane;
    ((ushort4*)oHi)[q4] = h4;
    ((ushort4*)oLo)[q4] = l4;
  }
}

// ---- single-head attention + ELU + lrelu + split-bf16 store (old attn2 mode 3) ----
__device__ __forceinline__ void attn2m3_body(
    const unsigned short* __restrict__ hB,
    const float* __restrict__ alpha, const float* __restrict__ beta,
    const float* __restrict__ ab, const int* __restrict__ cnt,
    const int* __restrict__ colb,
    unsigned short* __restrict__ oHi, unsigned short* __restrict__ oLo, int Nn) {
  const int tid = threadIdx.x;
  const int lane = tid & 63;
  const int wv = tid >> 6;
  const unsigned short* hLB = hB + (lane << 2);
  const float ab0 = ab[0];

  for (int u = blockIdx.x; u < (Nn >> 2); u += gridDim.x) {
    const int i = u * 4 + wv;
    const float ai = alpha[i] + ab0;
    const int start = i * MAXB;
    int len = cnt[i];
    if (len > MAXB) len = MAXB;

    float m = -3.0e38f, s = 0.0f;
    float4 acc0 = make_float4(0.0f, 0.0f, 0.0f, 0.0f);
    float4 acc1 = make_float4(0.0f, 0.0f, 0.0f, 0.0f);

    for (int t0 = 0; t0 < len; t0 += 64) {
      const int t = t0 + lane;
      const int c = (t < len) ? colb[start + t] : -1;
      float e = -3.0e38f;
      if (c >= 0) {
        e = ai + beta[c];
        e = e > 0.0f ? e : NEG_SLOPE * e;
      }
      float cm = e;
#pragma unroll
      for (int off = 32; off > 0; off >>= 1) cm = fmaxf(cm, __shfl_xor(cm, off, 64));
      const float newm = fmaxf(m, cm);
      const float scale = __expf(m - newm);
      const float w = (c >= 0) ? __expf(e - newm) : 0.0f;
      float cs = w;
#pragma unroll
      for (int off = 32; off > 0; off >>= 1) cs += __shfl_xor(cs, off, 64);
      s = s * scale + cs;
      acc0.x *= scale; acc0.y *= scale; acc0.z *= scale; acc0.w *= scale;
      acc1.x *= scale; acc1.y *= scale; acc1.z *= scale; acc1.w *= scale;
      m = newm;

      const int cS = (c >= 0) ? c : 0;
      const int cnt2 = min(64, len - t0);
      int j = 0;
      for (; j + 4 <= cnt2; j += 4) {
        const int c0 = __shfl(cS, j);     const float w0 = __shfl(w, j);
        const int c1 = __shfl(cS, j + 1); const float w1 = __shfl(w, j + 1);
        const int c2 = __shfl(cS, j + 2); const float w2 = __shfl(w, j + 2);
        const int c3 = __shfl(cS, j + 3); const float w3 = __shfl(w, j + 3);
        const ushort4 u0 = *(const ushort4*)(hLB + (size_t)c0 * D);
        const ushort4 u1 = *(const ushort4*)(hLB + (size_t)c1 * D);
        const ushort4 u2 = *(const ushort4*)(hLB + (size_t)c2 * D);
        const ushort4 u3 = *(const ushort4*)(hLB + (size_t)c3 * D);
        acc0.x += w0 * bf16_tof(u0.x); acc0.y += w0 * bf16_tof(u0.y);
        acc0.z += w0 * bf16_tof(u0.z); acc0.w += w0 * bf16_tof(u0.w);
        acc1.x += w1 * bf16_tof(u1.x); acc1.y += w1 * bf16_tof(u1.y);
        acc1.z += w1 * bf16_tof(u1.z); acc1.w += w1 * bf16_tof(u1.w);
        acc0.x += w2 * bf16_tof(u2.x); acc0.y += w2 * bf16_tof(u2.y);
        acc0.z += w2 * bf16_tof(u2.z); acc0.w += w2 * bf16_tof(u2.w);
        acc1.x += w3 * bf16_tof(u3.x); acc1.y += w3 * bf16_tof(u3.y);
        acc1.z += w3 * bf16_tof(u3.z); acc1.w += w3 * bf16_tof(u3.w);
      }
      for (; j < cnt2; ++j) {
        const int cj = __shfl(cS, j);
        const float wj = __shfl(w, j);
        const ushort4 uu = *(const ushort4*)(hLB + (size_t)cj * D);
        acc0.x += wj * bf16_tof(uu.x); acc0.y += wj * bf16_tof(uu.y);
        acc0.z += wj * bf16_tof(uu.z); acc0.w += wj * bf16_tof(uu.w);
      }
    }

    const float inv = 1.0f / s;
    float4 v;
    v.x = (acc0.x + acc1.x) * inv; v.y = (acc0.y + acc1.y) * inv;
    v.z = (acc0.z + acc1.z) * inv; v.w = (acc0.w + acc1.w) * inv;
    v.x = v.x > 0.0f ? v.x : expm1f(v.x);
    v.y = v.y > 0.0f ? v.y : expm1f(v.y);
    v.z = v.z > 0.0f ? v.z : expm1f(v.z);
    v.w = v.w > 0.0f ? v.w : expm1f(v.w);
    v.x = v.x > 0.0f ? v.x : NEG_SLOPE * v.x;
    v.y = v.y > 0.0f ? v.y : NEG_SLOPE * v.y;
    v.z = v.z > 0.0f ? v.z : NEG_SLOPE * v.z;
    v.w = v.w > 0.0f ? v.w : NEG_SLOPE * v.w;
    ushort4 h4, l4;
    split2(v.x, h4.x, l4.x);
    split2(v.y, h4.y, l4.y);
    split2(v.z, h4.z, l4.z);
    split2(v.w, h4.w, l4.w);
    const size_t q4 = ((size_t)i * D >> 2) + lane;
    ((ushort4*)oHi)[q4] = h4;
    ((ushort4*)oLo)[q4] = l4;
  }
}

// =================== R18: cooperative mega-kernel (whole mfma path, 1 dispatch) ===================
struct MegaArgs {
  int* zeroBase; int zeroN;
  const float* x; unsigned short* xhi; unsigned short* xlo; int xN4;
  const float* l0hW; unsigned short* l0hHi; unsigned short* l0hLo;
  const float* l1hW; unsigned short* l1hHi; unsigned short* l1hLo;
  const float* l0oW; unsigned short* l0oHi; unsigned short* l0oLo;
  const float* l1oW; unsigned short* l1oHi; unsigned short* l1oLo;
  const float* linW; unsigned short* linHi; unsigned short* linLo;
  const int* src; const int* dst; int* cnt; int* colb; int E; int Nn;
  unsigned short* hbufB; unsigned short* houtB;
  unsigned short* xmHi; unsigned short* xmLo;
  unsigned short* x1hi; unsigned short* x1lo;
  const float* l0_hWb; const float* l0_ha; const float* l0_hab;
  const float* l0_oWb; const float* l0_oa; const float* l0_oab;
  const float* l1_hWb; const float* l1_ha; const float* l1_hab;
  const float* l1_oWb; const float* l1_oa; const float* l1_oab;
  const float* lin_b; float* outF;
  float* aS0; float* bS0; float* aS1; float* bS1;
  float* aS2; float* bS2; float* aS3; float* bS3;
};

__global__ __launch_bounds__(256, 2) void mega_gat(MegaArgs a) {
  __shared__ __align__(16) unsigned short smemU[4 * 64 * 72];   // 36864 B (gemm union)
  unsigned short* sA0 = smemU;
  unsigned short* sA1 = smemU + 64 * 72;
  unsigned short* sB0 = smemU + 2 * 64 * 72;
  unsigned short* sB1 = smemU + 3 * 64 * 72;
  cg::grid_group grid = cg::this_grid();
  const int tilesX = a.Nn >> 6;

  prep_body(a.zeroBase, a.zeroN, a.x, a.xhi, a.xlo, a.xN4,
            a.l0hW, a.l0hHi, a.l0hLo, a.l1hW, a.l1hHi, a.l1hLo,
            a.l0oW, a.l0oHi, a.l0oLo, a.l1oW, a.l1oHi, a.l1oLo,
            a.linW, a.linHi, a.linLo, (float*)smemU);
  grid.sync();
  fill_body(a.src, a.dst, a.cnt, a.colb, a.E);
  grid.sync();
  dedupe_body(a.cnt, a.colb, a.Nn, (int*)smemU);
  grid.sync();
  // --- layer 0 ---
  gemm_body(a.xhi, a.xlo, a.l0hHi, a.l0hLo, a.l0_hWb, nullptr, a.hbufB,
            a.l0_ha, a.aS0, a.bS0, 256, 512, 4, tilesX, tilesX * 16, sA0, sA1, sB0, sB1);
  grid.sync();
  attn4_body(a.hbufB, a.aS0, a.bS0, a.l0_hab, a.cnt, a.colb, a.xmHi, a.xmLo, a.Nn);
  grid.sync();
  gemm_body(a.xmHi, a.xmLo, a.l0oHi, a.l0oLo, a.l0_oWb, nullptr, a.houtB,
            a.l0_oa, a.aS1, a.bS1, 256, 256, 1, tilesX, tilesX * 4, sA0, sA1, sB0, sB1);
  grid.sync();
  attn2m3_body(a.houtB, a.aS1, a.bS1, a.l0_oab, a.cnt, a.colb, a.x1hi, a.x1lo, a.Nn);
  grid.sync();
  // --- layer 1 ---
  gemm_body(a.x1hi, a.x1lo, a.l1hHi, a.l1hLo, a.l1_hWb, nullptr, a.hbufB,
            a.l1_ha, a.aS2, a.bS2, 256, 256, 4, tilesX, tilesX * 16, sA0, sA1, sB0, sB1);
  grid.sync();
  attn4_body(a.hbufB, a.aS2, a.bS2, a.l1_hab, a.cnt, a.colb, a.xmHi, a.xmLo, a.Nn);
  grid.sync();
  gemm_body(a.xmHi, a.xmLo, a.l1oHi, a.l1oLo, a.l1_oWb, nullptr, a.houtB,
            a.l1_oa, a.aS3, a.bS3, 256, 256, 1, tilesX, tilesX * 4, sA0, sA1, sB0, sB1);
  grid.sync();
  attn2m3_body(a.houtB, a.aS3, a.bS3, a.l1_oab, a.cnt, a.colb, a.x1hi, a.x1lo, a.Nn);
  grid.sync();
  // --- final linear (fp32 out) ---
  gemm_body(a.x1hi, a.x1lo, a.linHi, a.linLo, a.lin_b, a.outF, nullptr,
            nullptr, nullptr, nullptr, 128, 256, 1, tilesX, tilesX * 2, sA0, sA1, sB0, sB1);
}

// =================== thin global wrappers (fallback if cooperative launch fails) ===================
__global__ __launch_bounds__(256) void prep_kernel(
    int* zeroBase, int zeroN, const float* x, unsigned short* xhi, unsigned short* xlo, int xN4,
    const float* l0hW, unsigned short* l0hHi, unsigned short* l0hLo,
    const float* l1hW, unsigned short* l1hHi, unsigned short* l1hLo,
    const float* l0oW, unsigned short* l0oHi, unsigned short* l0oLo,
    const float* l1oW, unsigned short* l1oHi, unsigned short* l1oLo,
    const float* linW, unsigned short* linHi, unsigned short* linLo) {
  __shared__ __align__(16) float tileF[32 * 33];
  prep_body(zeroBase, zeroN, x, xhi, xlo, xN4, l0hW, l0hHi, l0hLo, l1hW, l1hHi, l1hLo,
            l0oW, l0oHi, l0oLo, l1oW, l1oHi, l1oLo, linW, linHi, linLo, tileF);
}

__global__ void fill_kernel(const int* src, const int* dst, int* cnt, int* colb, int E) {
  fill_body(src, dst, cnt, colb, E);
}

__global__ __launch_bounds__(256) void dedupe2_kernel(const int* cnt, int* colb, int Nn) {
  __shared__ int cs[256];
  dedupe_body(cnt, colb, Nn, cs);
}

__global__ __launch_bounds__(256) void gemm_k(
    const unsigned short* Ahi, const unsigned short* Alo,
    const unsigned short* Bthi, const unsigned short* Btlo,
    const float* bias, float* C, unsigned short* Cb,
    const float* aptr, float* alphaB, float* betaB,
    int N, int K, int Htot, int tilesX, int tilesTotal) {
  __shared__ __align__(16) unsigned short smemU[4 * 64 * 72];
  gemm_body(Ahi, Alo, Bthi, Btlo, bias, C, Cb, aptr, alphaB, betaB,
            N, K, Htot, tilesX, tilesTotal,
            smemU, smemU + 64 * 72, smemU + 2 * 64 * 72, smemU + 3 * 64 * 72);
}

__global__ __launch_bounds__(256) void attn4_kernel(
    const unsigned short* hB, const float* alpha, const float* beta, const float* ab,
    const int* cnt, const int* colb, unsigned short* oHi, unsigned short* oLo, int Nn) {
  attn4_body(hB, alpha, beta, ab, cnt, colb, oHi, oLo, Nn);
}

__global__ __launch_bounds__(256) void attn2m3_kernel(
    const unsigned short* hB, const float* alpha, const float* beta, const float* ab,
    const int* cnt, const int* colb, unsigned short* oHi, unsigned short* oLo, int Nn) {
  attn2m3_body(hB, alpha, beta, ab, cnt, colb, oHi, oLo, Nn);
}

// =================== fp32 fallback-path kernels (small-ws only, unchanged) ===================
__global__ __launch_bounds__(256) void gemm_bias(
    const float* __restrict__ A, const float* __restrict__ B,
    const float* __restrict__ bias, float* __restrict__ C,
    int M, int N, int K) {
  __shared__ float As[16][68];
  __shared__ float Bs[16][68];
  const int tid = threadIdx.x;
  const int bm = blockIdx.x * 64;
  const int gn = blockIdx.y * 64;
  const int head = gn / N;
  const int bn = gn - head * N;
  const float* Bh = B + (size_t)head * K * N;
  const int tx = tid & 15;
  const int ty = tid >> 4;
  const int am = tid >> 2;
  const int ak = (tid & 3) << 2;
  const int bk = tid >> 4;
  const int bn4 = (tid & 15) << 2;
  float acc[4][4] = {};
  for (int k0 = 0; k0 < K; k0 += 16) {
    float4 av = *(const float4*)(A + (size_t)(bm + am) * K + (k0 + ak));
    float4 bv = *(const float4*)(Bh + (size_t)(k0 + bk) * N + (bn + bn4));
    __syncthreads();
    As[ak + 0][am] = av.x;
    As[ak + 1][am] = av.y;
    As[ak + 2][am] = av.z;
    As[ak + 3][am] = av.w;
    *(float4*)(&Bs[bk][bn4]) = bv;
    __syncthreads();
#pragma unroll
    for (int k = 0; k < 16; ++k) {
      float4 aa = *(const float4*)(&As[k][ty << 2]);
      float4 bb = *(const float4*)(&Bs[k][tx << 2]);
      acc[0][0] += aa.x * bb.x; acc[0][1] += aa.x * bb.y; acc[0][2] += aa.x * bb.z; acc[0][3] += aa.x * bb.w;
      acc[1][0] += aa.y * bb.x; acc[1][1] += aa.y * bb.y; acc[1][2] += aa.y * bb.z; acc[1][3] += aa.y * bb.w;
      acc[2][0] += aa.z * bb.x; acc[2][1] += aa.z * bb.y; acc[2][2] += aa.z * bb.z; acc[2][3] += aa.z * bb.w;
      acc[3][0] += aa.w * bb.x; acc[3][1] += aa.w * bb.y; acc[3][2] += aa.w * bb.z; acc[3][3] += aa.w * bb.w;
    }
  }
  float* Ch = C + (size_t)head * M * N;
  const float* bh = bias + (size_t)head * N;
  const int ccol = bn + (tx << 2);
  float4 bias4 = *(const float4*)(bh + ccol);
#pragma unroll
  for (int r = 0; r < 4; ++r) {
    int row = bm + (ty << 2) + r;
    float4 o;
    o.x = acc[r][0] + bias4.x;
    o.y = acc[r][1] + bias4.y;
    o.z = acc[r][2] + bias4.z;
    o.w = acc[r][3] + bias4.w;
    *(float4*)(Ch + (size_t)row * N + ccol) = o;
  }
}

__global__ __launch_bounds__(256) void alphabeta_kernel(
    const float* __restrict__ h, const float* __restrict__ a,
    float* __restrict__ alpha, float* __restrict__ beta, int Nn) {
  __shared__ float reda[4], redb[4];
  const int i = blockIdx.x;
  const int hh = blockIdx.y;
  const int tid = threadIdx.x;
  const int lane = tid & 63, wid = tid >> 6;
  float v = h[((size_t)hh * Nn + i) * D + tid];
  float pa = v * a[hh * 2 * D + tid];
  float pb = v * a[hh * 2 * D + D + tid];
#pragma unroll
  for (int off = 32; off > 0; off >>= 1) {
    pa += __shfl_xor(pa, off, 64);
    pb += __shfl_xor(pb, off, 64);
  }
  if (lane == 0) { reda[wid] = pa; redb[wid] = pb; }
  __syncthreads();
  if (tid == 0) {
    alpha[hh * Nn + i] = reda[0] + reda[1] + reda[2] + reda[3];
    beta[hh * Nn + i] = redb[0] + redb[1] + redb[2] + redb[3];
  }
}

// fp32 fused sparse attention (fallback path only; modes 0/1/2)
__global__ __launch_bounds__(256) void attn2f(
    const float* __restrict__ h,
    const float* __restrict__ alpha, const float* __restrict__ beta,
    const float* __restrict__ ab, const int* __restrict__ cnt,
    const int* __restrict__ colb, float* __restrict__ out,
    int Nn, int H, int mode) {
  const int tid = threadIdx.x;
  const int lane = tid & 63;
  const int wv = tid >> 6;
  const int bx = blockIdx.x;
  const int head = bx % H;
  const int rowblk = bx / H;
  const int i = rowblk * 4 + wv;

  const float* hL = h + (size_t)head * Nn * D + (lane << 2);
  const float* betaH = beta + (size_t)head * Nn;
  const float ai = alpha[head * Nn + i] + ab[head];
  const int start = i * MAXB;
  int len = cnt[i];
  if (len > MAXB) len = MAXB;

  float m = -3.0e38f, s = 0.0f;
  float4 acc0 = make_float4(0.0f, 0.0f, 0.0f, 0.0f);
  float4 acc1 = make_float4(0.0f, 0.0f, 0.0f, 0.0f);

  for (int t0 = 0; t0 < len; t0 += 64) {
    const int t = t0 + lane;
    const int c = (t < len) ? colb[start + t] : -1;
    float e = -3.0e38f;
    if (c >= 0) {
      e = ai + betaH[c];
      e = e > 0.0f ? e : NEG_SLOPE * e;
    }
    float cm = e;
#pragma unroll
    for (int off = 32; off > 0; off >>= 1) cm = fmaxf(cm, __shfl_xor(cm, off, 64));
    const float newm = fmaxf(m, cm);
    const float scale = __expf(m - newm);
    const float w = (c >= 0) ? __expf(e - newm) : 0.0f;
    float cs = w;
#pragma unroll
    for (int off = 32; off > 0; off >>= 1) cs += __shfl_xor(cs, off, 64);
    s = s * scale + cs;
    acc0.x *= scale; acc0.y *= scale; acc0.z *= scale; acc0.w *= scale;
    acc1.x *= scale; acc1.y *= scale; acc1.z *= scale; acc1.w *= scale;
    m = newm;

    const int cS = (c >= 0) ? c : 0;
    const int cnt2 = min(64, len - t0);
    int j = 0;
    for (; j + 4 <= cnt2; j += 4) {
      const int c0 = __shfl(cS, j);     const float w0 = __shfl(w, j);
      const int c1 = __shfl(cS, j + 1); const float w1 = __shfl(w, j + 1);
      const int c2 = __shfl(cS, j + 2); const float w2 = __shfl(w, j + 2);
      const int c3 = __shfl(cS, j + 3); const float w3 = __shfl(w, j + 3);
      const float4 h0 = *(const float4*)(hL + (size_t)c0 * D);
      const float4 h1 = *(const float4*)(hL + (size_t)c1 * D);
      const float4 h2 = *(const float4*)(hL + (size_t)c2 * D);
      const float4 h3 = *(const float4*)(hL + (size_t)c3 * D);
      acc0.x += w0 * h0.x; acc0.y += w0 * h0.y; acc0.z += w0 * h0.z; acc0.w += w0 * h0.w;
      acc1.x += w1 * h1.x; acc1.y += w1 * h1.y; acc1.z += w1 * h1.z; acc1.w += w1 * h1.w;
      acc0.x += w2 * h2.x; acc0.y += w2 * h2.y; acc0.z += w2 * h2.z; acc0.w += w2 * h2.w;
      acc1.x += w3 * h3.x; acc1.y += w3 * h3.y; acc1.z += w3 * h3.z; acc1.w += w3 * h3.w;
    }
    for (; j < cnt2; ++j) {
      const int cj = __shfl(cS, j);
      const float wj = __shfl(w, j);
      const float4 hv = *(const float4*)(hL + (size_t)cj * D);
      acc0.x += wj * hv.x; acc0.y += wj * hv.y;
      acc0.z += wj * hv.z; acc0.w += wj * hv.w;
    }
  }

  const float inv = 1.0f / s;
  float4 v;
  v.x = (acc0.x + acc1.x) * inv; v.y = (acc0.y + acc1.y) * inv;
  v.z = (acc0.z + acc1.z) * inv; v.w = (acc0.w + acc1.w) * inv;
  v.x = v.x > 0.0f ? v.x : expm1f(v.x);
  v.y = v.y > 0.0f ? v.y : expm1f(v.y);
  v.z = v.z > 0.0f ? v.z : expm1f(v.z);
  v.w = v.w > 0.0f ? v.w : expm1f(v.w);

  if (mode == 1) {
    v.x = v.x > 0.0f ? v.x : NEG_SLOPE * v.x;
    v.y = v.y > 0.0f ? v.y : NEG_SLOPE * v.y;
    v.z = v.z > 0.0f ? v.z : NEG_SLOPE * v.z;
    v.w = v.w > 0.0f ? v.w : NEG_SLOPE * v.w;
    *(float4*)(out + (size_t)i * D + (lane << 2)) = v;
  } else if (mode == 0) {
    *(float4*)(out + ((size_t)head * Nn + i) * D + (lane << 2)) = v;
  } else {
    const float invH = 1.0f / (float)H;
    float* o = out + (size_t)i * D + (lane << 2);
    atomicAdd(o + 0, invH * v.x);
    atomicAdd(o + 1, invH * v.y);
    atomicAdd(o + 2, invH * v.z);
    atomicAdd(o + 3, invH * v.w);
  }
}

__global__ __launch_bounds__(256) void mean4_kernel(float* __restrict__ hsep, int total4) {
  int idx = blockIdx.x * blockDim.x + threadIdx.x;
  if (idx < total4) {
    float4* p = (float4*)hsep;
    float4 a = p[idx], b = p[idx + total4], c = p[idx + 2 * total4], d = p[idx + 3 * total4];
    float4 o;
    o.x = 0.25f * (a.x + b.x + c.x + d.x);
    o.y = 0.25f * (a.y + b.y + c.y + d.y);
    o.z = 0.25f * (a.z + b.z + c.z + d.z);
    o.w = 0.25f * (a.w + b.w + c.w + d.w);
    p[idx] = o;
  }
}

__global__ void zero_ints(int* __restrict__ p, int n) {
  int i = blockIdx.x * blockDim.x + threadIdx.x;
  if (i < n) p[i] = 0;
}

__global__ void zero_floats(float* __restrict__ p, int n) {
  int i = blockIdx.x * blockDim.x + threadIdx.x;
  if (i < n) p[i] = 0.0f;
}

// ---------------- host ----------------
extern "C" void kernel_launch(void* const* d_in, const int* in_sizes, int n_in,
                              void* d_out, int out_size, void* d_ws, size_t ws_size,
                              hipStream_t stream) {
  const float* x = (const float*)d_in[0];
  const int* eidx = (const int*)d_in[1];
  const float* l0_hW = (const float*)d_in[2];
  const float* l0_hWb = (const float*)d_in[3];
  const float* l0_ha = (const float*)d_in[4];
  const float* l0_hab = (const float*)d_in[5];
  const float* l0_oW = (const float*)d_in[6];
  const float* l0_oWb = (const float*)d_in[7];
  const float* l0_oa = (const float*)d_in[8];
  const float* l0_oab = (const float*)d_in[9];
  const float* l1_hW = (const float*)d_in[10];
  const float* l1_hWb = (const float*)d_in[11];
  const float* l1_ha = (const float*)d_in[12];
  const float* l1_hab = (const float*)d_in[13];
  const float* l1_oW = (const float*)d_in[14];
  const float* l1_oWb = (const float*)d_in[15];
  const float* l1_oa = (const float*)d_in[16];
  const float* l1_oab = (const float*)d_in[17];
  const float* lin_W = (const float*)d_in[18];
  const float* lin_b = (const float*)d_in[19];

  const int in_dim = 512;
  const int Nn = in_sizes[0] / in_dim;  // 4096
  const int E = in_sizes[1] / 2;        // 131072
  const int out_dim = 128;

  char* wsp = (char*)d_ws;
  auto alloc = [&](size_t bytes) {
    char* p = wsp;
    wsp += (bytes + 255) & ~(size_t)255;
    return p;
  };
  const size_t ndBytes = sizeof(float) * (size_t)Nn * D;        // 4 MB
  const size_t mfmaNeed = 52000000;
  const bool mfma = ws_size >= mfmaNeed;

  if (mfma) {
    unsigned short* hbufB = (unsigned short*)alloc((size_t)HEADS * Nn * D * 2); // [row][head][D] bf16
    unsigned short* houtB = (unsigned short*)alloc((size_t)Nn * D * 2);
    unsigned short* xmHi  = (unsigned short*)alloc((size_t)Nn * D * 2);
    unsigned short* xmLo  = (unsigned short*)alloc((size_t)Nn * D * 2);
    unsigned short* xhi  = (unsigned short*)alloc((size_t)Nn * in_dim * 2);
    unsigned short* xlo  = (unsigned short*)alloc((size_t)Nn * in_dim * 2);
    unsigned short* x1hi = xhi;                                  // alias: x dead after L0 head gemm
    unsigned short* x1lo = xlo;
    unsigned short* l0hHi = (unsigned short*)alloc((size_t)HEADS * in_dim * D * 2);
    unsigned short* l0hLo = (unsigned short*)alloc((size_t)HEADS * in_dim * D * 2);
    unsigned short* l1hHi = (unsigned short*)alloc((size_t)HEADS * D * D * 2);
    unsigned short* l1hLo = (unsigned short*)alloc((size_t)HEADS * D * D * 2);
    unsigned short* l0oHi = (unsigned short*)alloc((size_t)D * D * 2);
    unsigned short* l0oLo = (unsigned short*)alloc((size_t)D * D * 2);
    unsigned short* l1oHi = (unsigned short*)alloc((size_t)D * D * 2);
    unsigned short* l1oLo = (unsigned short*)alloc((size_t)D * D * 2);
    unsigned short* linHi = (unsigned short*)alloc((size_t)D * out_dim * 2);
    unsigned short* linLo = (unsigned short*)alloc((size_t)D * out_dim * 2);
    int* cnt     = (int*)alloc(sizeof(int) * Nn);
    float* abz   = (float*)alloc(sizeof(float) * 4 * 2 * HEADS * (size_t)Nn);
    int* colb    = (int*)alloc(sizeof(int) * (size_t)Nn * MAXB);
    auto alphaS = [&](int s) { return abz + (size_t)s * 2 * HEADS * Nn; };
    auto betaS  = [&](int s) { return abz + (size_t)s * 2 * HEADS * Nn + HEADS * Nn; };

    const int* src = eidx;
    const int* dst = eidx + E;
    const int zeroN = Nn + 4 * 2 * HEADS * Nn;   // 135168
    const int tilesX = Nn / 64;

    // ---- R18: one cooperative dispatch for the whole path ----
    MegaArgs ma;
    ma.zeroBase = cnt; ma.zeroN = zeroN;
    ma.x = x; ma.xhi = xhi; ma.xlo = xlo; ma.xN4 = Nn * in_dim / 4;
    ma.l0hW = l0_hW; ma.l0hHi = l0hHi; ma.l0hLo = l0hLo;
    ma.l1hW = l1_hW; ma.l1hHi = l1hHi; ma.l1hLo = l1hLo;
    ma.l0oW = l0_oW; ma.l0oHi = l0oHi; ma.l0oLo = l0oLo;
    ma.l1oW = l1_oW; ma.l1oHi = l1oHi; ma.l1oLo = l1oLo;
    ma.linW = lin_W; ma.linHi = linHi; ma.linLo = linLo;
    ma.src = src; ma.dst = dst; ma.cnt = cnt; ma.colb = colb; ma.E = E; ma.Nn = Nn;
    ma.hbufB = hbufB; ma.houtB = houtB;
    ma.xmHi = xmHi; ma.xmLo = xmLo; ma.x1hi = x1hi; ma.x1lo = x1lo;
    ma.l0_hWb = l0_hWb; ma.l0_ha = l0_ha; ma.l0_hab = l0_hab;
    ma.l0_oWb = l0_oWb; ma.l0_oa = l0_oa; ma.l0_oab = l0_oab;
    ma.l1_hWb = l1_hWb; ma.l1_ha = l1_ha; ma.l1_hab = l1_hab;
    ma.l1_oWb = l1_oWb; ma.l1_oa = l1_oa; ma.l1_oab = l1_oab;
    ma.lin_b = lin_b; ma.outF = (float*)d_out;
    ma.aS0 = alphaS(0); ma.bS0 = betaS(0);
    ma.aS1 = alphaS(1); ma.bS1 = betaS(1);
    ma.aS2 = alphaS(2); ma.bS2 = betaS(2);
    ma.aS3 = alphaS(3); ma.bS3 = betaS(3);

    int nbk = 0;
    hipError_t qe = hipOccupancyMaxActiveBlocksPerMultiprocessor(&nbk, mega_gat, 256, 0);
    if (qe != hipSuccess) nbk = 0;
    if (nbk > 2) nbk = 2;
    if (nbk >= 1) {
      void* kargs[] = {(void*)&ma};
      hipError_t le = hipLaunchCooperativeKernel(mega_gat, dim3(nbk * 256), dim3(256),
                                                 kargs, 0, stream);
      if (le == hipSuccess) return;
      (void)hipGetLastError();   // clear; fall through to multi-dispatch path
    }

    // ---- fallback: 12-dispatch path over the same bodies ----
    prep_kernel<<<3536, 256, 0, stream>>>(
        cnt, zeroN, x, xhi, xlo, Nn * in_dim / 4,
        l0_hW, l0hHi, l0hLo, l1_hW, l1hHi, l1hLo,
        l0_oW, l0oHi, l0oLo, l1_oW, l1oHi, l1oLo, lin_W, linHi, linLo);
    fill_kernel<<<(E + 255) / 256, 256, 0, stream>>>(src, dst, cnt, colb, E);
    dedupe2_kernel<<<Nn / 2, 256, 0, stream>>>(cnt, colb, Nn);

    gemm_k<<<tilesX * 16, 256, 0, stream>>>(xhi, xlo, l0hHi, l0hLo, l0_hWb, nullptr, hbufB,
                                            l0_ha, alphaS(0), betaS(0), 256, 512, 4, tilesX, tilesX * 16);
    attn4_kernel<<<Nn / 4, 256, 0, stream>>>(hbufB, alphaS(0), betaS(0), l0_hab, cnt, colb, xmHi, xmLo, Nn);
    gemm_k<<<tilesX * 4, 256, 0, stream>>>(xmHi, xmLo, l0oHi, l0oLo, l0_oWb, nullptr, houtB,
                                           l0_oa, alphaS(1), betaS(1), 256, 256, 1, tilesX, tilesX * 4);
    attn2m3_kernel<<<Nn / 4, 256, 0, stream>>>(houtB, alphaS(1), betaS(1), l0_oab, cnt, colb, x1hi, x1lo, Nn);

    gemm_k<<<tilesX * 16, 256, 0, stream>>>(x1hi, x1lo, l1hHi, l1hLo, l1_hWb, nullptr, hbufB,
                                            l1_ha, alphaS(2), betaS(2), 256, 256, 4, tilesX, tilesX * 16);
    attn4_kernel<<<Nn / 4, 256, 0, stream>>>(hbufB, alphaS(2), betaS(2), l1_hab, cnt, colb, xmHi, xmLo, Nn);
    gemm_k<<<tilesX * 4, 256, 0, stream>>>(xmHi, xmLo, l1oHi, l1oLo, l1_oWb, nullptr, houtB,
                                           l1_oa, alphaS(3), betaS(3), 256, 256, 1, tilesX, tilesX * 4);
    attn2m3_kernel<<<Nn / 4, 256, 0, stream>>>(houtB, alphaS(3), betaS(3), l1_oab, cnt, colb, x1hi, x1lo, Nn);

    gemm_k<<<tilesX * 2, 256, 0, stream>>>(x1hi, x1lo, linHi, linLo, lin_b, (float*)d_out, nullptr,
                                           nullptr, nullptr, nullptr, 128, 256, 1, tilesX, tilesX * 2);
    return;
  }

  // ================= fallback: fp32 path (bucketed CSR) =================
  const size_t smallBytes = sizeof(float) * 2 * HEADS * (size_t)Nn + sizeof(int) * (Nn + (size_t)Nn * MAXB) + 4096;
  const bool staged = ws_size >= (8 * ndBytes + 2 * ndBytes + smallBytes + 65536);

  float* hbuf  = (float*)alloc(ndBytes * HEADS);
  float* hsep  = staged ? (float*)alloc(ndBytes * HEADS) : nullptr;
  float* xm    = staged ? hsep : (float*)alloc(ndBytes);
  float* x1    = (float*)alloc(ndBytes);
  float* hout  = (float*)alloc(ndBytes);
  float* alpha = (float*)alloc(sizeof(float) * HEADS * (size_t)Nn);
  float* beta  = (float*)alloc(sizeof(float) * HEADS * (size_t)Nn);
  int* cnt     = (int*)alloc(sizeof(int) * Nn);
  int* colb    = (int*)alloc(sizeof(int) * (size_t)Nn * MAXB);

  const int* src = eidx;
  const int* dst = eidx + E;

  zero_ints<<<(Nn + 255) / 256, 256, 0, stream>>>(cnt, Nn);
  fill_kernel<<<(E + 255) / 256, 256, 0, stream>>>(src, dst, cnt, colb, E);
  dedupe2_kernel<<<Nn / 2, 256, 0, stream>>>(cnt, colb, Nn);

  const int total4 = Nn * D / 4;
  const int meanBlocks = (total4 + 255) / 256;

  gemm_bias<<<dim3(Nn / 64, HEADS * D / 64), 256, 0, stream>>>(x, l0_hW, l0_hWb, hbuf, Nn, D, in_dim);
  alphabeta_kernel<<<dim3(Nn, HEADS), 256, 0, stream>>>(hbuf, l0_ha, alpha, beta, Nn);
  if (staged) {
    attn2f<<<HEADS * (Nn / 4), 256, 0, stream>>>(hbuf, alpha, beta, l0_hab, cnt, colb, hsep, Nn, HEADS, 0);
    mean4_kernel<<<meanBlocks, 256, 0, stream>>>(hsep, total4);
  } else {
    zero_floats<<<(Nn * D + 255) / 256, 256, 0, stream>>>(xm, Nn * D);
    attn2f<<<HEADS * (Nn / 4), 256, 0, stream>>>(hbuf, alpha, beta, l0_hab, cnt, colb, xm, Nn, HEADS, 2);
  }
  gemm_bias<<<dim3(Nn / 64, D / 64), 256, 0, stream>>>(xm, l0_oW, l0_oWb, hout, Nn, D, D);
  alphabeta_kernel<<<dim3(Nn, 1), 256, 0, stream>>>(hout, l0_oa, alpha, beta, Nn);
  attn2f<<<Nn / 4, 256, 0, stream>>>(hout, alpha, beta, l0_oab, cnt, colb, x1, Nn, 1, 1);

  gemm_bias<<<dim3(Nn / 64, HEADS * D / 64), 256, 0, stream>>>(x1, l1_hW, l1_hWb, hbuf, Nn, D, D);
  alphabeta_kernel<<<dim3(Nn, HEADS), 256, 0, stream>>>(hbuf, l1_ha, alpha, beta, Nn);
  if (staged) {
    attn2f<<<HEADS * (Nn / 4), 256, 0, stream>>>(hbuf, alpha, beta, l1_hab, cnt, colb, hsep, Nn, HEADS, 0);
    mean4_kernel<<<meanBlocks, 256, 0, stream>>>(hsep, total4);
  } else {
    zero_floats<<<(Nn * D + 255) / 256, 256, 0, stream>>>(xm, Nn * D);
    attn2f<<<HEADS * (Nn / 4), 256, 0, stream>>>(hbuf, alpha, beta, l1_hab, cnt, colb, xm, Nn, HEADS, 2);
  }
  gemm_bias<<<dim3(Nn / 64, D / 64), 256, 0, stream>>>(xm, l1_oW, l1_oWb, hout, Nn, D, D);
  alphabeta_kernel<<<dim3(Nn, 1), 256, 0, stream>>>(hout, l1_oa, alpha, beta, Nn);
  attn2f<<<Nn / 4, 256, 0, stream>>>(hout, alpha, beta, l1_oab, cnt, colb, x1, Nn, 1, 1);

  gemm_bias<<<dim3(Nn / 64, out_dim / 64), 256, 0, stream>>>(x1, lin_W, lin_b, (float*)d_out, Nn, out_dim, D);
}

// Round 7
// 265.658 us; speedup vs baseline: 2.6051x; 2.6051x over previous
//
#include <hip/hip_runtime.h>
#include <hip/hip_bf16.h>
#include <math.h>

#define NEG_SLOPE 0.2f

constexpr int D = 256;       // hid width (all attention stages use D=256)
constexpr int HEADS = 4;
constexpr int MAXB = 128;    // fixed bucket stride; deg ~ Poisson(32), P(>128) ~ 0

typedef __attribute__((ext_vector_type(8))) short short8;   // bf16x8 MFMA frag (4 VGPR)
typedef __attribute__((ext_vector_type(4))) float floatx4;  // fp32 accumulator

// ---------------- bf16 split helpers: v ~= hi + lo, rel err ~2^-16 ----------------
__device__ inline unsigned short bf16_hi_trunc(float v) {
  return (unsigned short)(__float_as_uint(v) >> 16);
}
__device__ inline float bf16_tof(unsigned short u) {
  return __uint_as_float(((unsigned int)u) << 16);
}
__device__ inline unsigned short bf16_rn(float v) {
  unsigned int b = __float_as_uint(v);
  b += 0x7fffu + ((b >> 16) & 1u);
  return (unsigned short)(b >> 16);
}
__device__ inline void split2(float v, unsigned short& hi, unsigned short& lo) {
  hi = bf16_hi_trunc(v);
  lo = bf16_rn(v - bf16_tof(hi));
}

// ---------------- bucketed CSR build ----------------
__global__ void fill_kernel(const int* __restrict__ src, const int* __restrict__ dst,
                            int* __restrict__ cnt, int* __restrict__ colb, int E) {
  int k = blockIdx.x * blockDim.x + threadIdx.x;
  if (k < E) {
    int s = src[k];
    int pos = atomicAdd(&cnt[s], 1);
    if (pos < MAXB) colb[s * MAXB + pos] = dst[k];
  }
}

// dedupe: 2 rows per 256-thread block
__global__ __launch_bounds__(256) void dedupe2_kernel(const int* __restrict__ cnt,
                                                      int* __restrict__ colb, int Nn) {
  __shared__ int cs[256];
  const int sub = threadIdx.x >> 7;        // 0/1
  const int t7 = threadIdx.x & 127;
  const int i = (blockIdx.x << 1) + sub;
  int len = cnt[i];
  if (len > MAXB) len = MAXB;
  if (t7 < len) cs[(sub << 7) + t7] = colb[i * MAXB + t7];
  __syncthreads();
  if (t7 < len) {
    int c = cs[(sub << 7) + t7];
    bool dup = false;
    for (int s2 = 0; s2 < t7; ++s2)
      if (cs[(sub << 7) + s2] == c) { dup = true; break; }
    if (dup) colb[i * MAXB + t7] = -1;
  }
}

// ---------------- merged prep: zeroing + x split + all weight transposes ----------------
__global__ __launch_bounds__(256) void prep_kernel(
    int* __restrict__ zeroBase, int zeroN,
    const float* __restrict__ x, unsigned short* __restrict__ xhi, unsigned short* __restrict__ xlo,
    int xN4,
    const float* __restrict__ l0hW, unsigned short* __restrict__ l0hHi, unsigned short* __restrict__ l0hLo,
    const float* __restrict__ l1hW, unsigned short* __restrict__ l1hHi, unsigned short* __restrict__ l1hLo,
    const float* __restrict__ l0oW, unsigned short* __restrict__ l0oHi, unsigned short* __restrict__ l0oLo,
    const float* __restrict__ l1oW, unsigned short* __restrict__ l1oHi, unsigned short* __restrict__ l1oLo,
    const float* __restrict__ linW, unsigned short* __restrict__ linHi, unsigned short* __restrict__ linLo) {
  const int b = blockIdx.x;
  const int t = threadIdx.x;
  if (b < 528) {
    int idx = b * 256 + t;
    if (idx < zeroN) zeroBase[idx] = 0;
    return;
  }
  if (b < 2576) {
    int idx = (b - 528) * 256 + t;
    if (idx < xN4) {
      float4 v = ((const float4*)x)[idx];
      ushort4 h, l;
      split2(v.x, h.x, l.x);
      split2(v.y, h.y, l.y);
      split2(v.z, h.z, l.z);
      split2(v.w, h.w, l.w);
      ((ushort4*)xhi)[idx] = h;
      ((ushort4*)xlo)[idx] = l;
    }
    return;
  }
  __shared__ float tile[32][33];
  const int tr = t >> 5, tc = t & 31;
  if (b < 3088) {                       // l0_hW: K=512, N=256, 4 heads
    const int bi = b - 2576;
    const int kb = bi & 15;
    const int nb = (bi >> 4) & 7;
    const int h = bi >> 7;
    const int K = 512, N = 256;
    const int k0 = kb * 32, n0 = nb * 32;
    const float* B = l0hW + (size_t)h * K * N;
#pragma unroll
    for (int i = 0; i < 4; ++i)
      tile[tr + 8 * i][tc] = B[(size_t)(k0 + tr + 8 * i) * N + (n0 + tc)];
    __syncthreads();
    unsigned short* Thi = l0hHi + (size_t)h * N * K;
    unsigned short* Tlo = l0hLo + (size_t)h * N * K;
#pragma unroll
    for (int i = 0; i < 4; ++i) {
      int n = n0 + tr + 8 * i, k = k0 + tc;
      float v = tile[tc][tr + 8 * i];
      unsigned short hi, lo;
      split2(v, hi, lo);
      Thi[(size_t)n * K + k] = hi;
      Tlo[(size_t)n * K + k] = lo;
    }
    return;
  }
  // 7-slice section (all K=256)
  const int bi = b - 3088;
  const int kb = bi & 7;
  const int nb = (bi >> 3) & 7;
  const int z = bi >> 6;
  const int K = 256;
  const int N = (z == 6) ? 128 : 256;
  const int k0 = kb * 32, n0 = nb * 32;
  if (n0 >= N) return;
  const float* B;
  unsigned short *Thi, *Tlo;
  if (z < 4) {
    B = l1hW + (size_t)z * K * 256;
    Thi = l1hHi + (size_t)z * 256 * K;
    Tlo = l1hLo + (size_t)z * 256 * K;
  } else if (z == 4) { B = l0oW; Thi = l0oHi; Tlo = l0oLo; }
  else if (z == 5)   { B = l1oW; Thi = l1oHi; Tlo = l1oLo; }
  else               { B = linW; Thi = linHi; Tlo = linLo; }
#pragma unroll
  for (int i = 0; i < 4; ++i)
    tile[tr + 8 * i][tc] = B[(size_t)(k0 + tr + 8 * i) * N + (n0 + tc)];
  __syncthreads();
#pragma unroll
  for (int i = 0; i < 4; ++i) {
    int n = n0 + tr + 8 * i, k = k0 + tc;
    float v = tile[tc][tr + 8 * i];
    unsigned short hi, lo;
    split2(v, hi, lo);
    Thi[(size_t)n * K + k] = hi;
    Tlo[(size_t)n * K + k] = lo;
  }
}

// ---------------- split-bf16 MFMA GEMM (64x64 tile, R15 pipelined loop) ----------------
// Flat grid: tile tt -> bm = (tt % tilesX)*64, gn = (tt / tilesX)*64 (flat over Htot*N).
// Output: Cb != nullptr -> bf16-rn [row][Htot][N]; else fp32 C [row][N].
// aptr != nullptr: fused alphabeta epilogue, alphaB/betaB laid [row][Htot] (pre-zeroed).
// R14/R15: raw s_barrier + lgkmcnt(0)-only publish; staging loads for tile k+1 stay in
// flight across the publish barrier (no vmcnt drain per K-step).
__global__ __launch_bounds__(256) void gemm_k(
    const unsigned short* __restrict__ Ahi, const unsigned short* __restrict__ Alo,
    const unsigned short* __restrict__ Bthi, const unsigned short* __restrict__ Btlo,
    const float* __restrict__ bias, float* __restrict__ C, unsigned short* __restrict__ Cb,
    const float* __restrict__ aptr, float* __restrict__ alphaB, float* __restrict__ betaB,
    int N, int K, int Htot, int tilesX) {
  constexpr int LSTR = 72;
  __shared__ unsigned short sA0[64 * LSTR];
  __shared__ unsigned short sA1[64 * LSTR];
  __shared__ unsigned short sB0[64 * LSTR];
  __shared__ unsigned short sB1[64 * LSTR];
  const int tid = threadIdx.x;
  const int tt = blockIdx.x;
  const int bm = (tt % tilesX) << 6;
  const int gn = (tt / tilesX) << 6;
  const int head = gn / N;
  const int bn = gn - head * N;

  const int lane = tid & 63;
  const int wv = tid >> 6;
  const int wm = (wv & 1) * 32;
  const int wn = (wv >> 1) * 32;
  const int q = lane >> 4;
  const int l15 = lane & 15;
  const size_t rowStride = (size_t)Htot * N;

  floatx4 acc[2][2];
#pragma unroll
  for (int i = 0; i < 2; ++i)
#pragma unroll
    for (int j = 0; j < 2; ++j) acc[i][j] = (floatx4)0.0f;

  short8 ra[2][2], rb[2][2];
#pragma unroll
  for (int i = 0; i < 2; ++i) {   // prologue: tile 0
    const int c = tid + 256 * i;
    const int row = c >> 3, koff = (c & 7) << 3;
    rb[0][i] = *(const short8*)(Bthi + (size_t)(gn + row) * K + koff);
    rb[1][i] = *(const short8*)(Btlo + (size_t)(gn + row) * K + koff);
    ra[0][i] = *(const short8*)(Ahi + (size_t)(bm + row) * K + koff);
    ra[1][i] = *(const short8*)(Alo + (size_t)(bm + row) * K + koff);
  }

  for (int k0 = 0; k0 < K; k0 += 64) {
    __builtin_amdgcn_s_barrier();      // barrier A: prev tile's LDS reads consumed
    __builtin_amdgcn_sched_barrier(0);
#pragma unroll
    for (int i = 0; i < 2; ++i) {
      const int c = tid + 256 * i;
      const int row = c >> 3, koff = (c & 7) << 3;
      *(short8*)(&sA0[row * LSTR + koff]) = ra[0][i];
      *(short8*)(&sA1[row * LSTR + koff]) = ra[1][i];
      *(short8*)(&sB0[row * LSTR + koff]) = rb[0][i];
      *(short8*)(&sB1[row * LSTR + koff]) = rb[1][i];
    }
    if (k0 + 64 < K) {   // next-tile loads stay in flight across barrier B
#pragma unroll
      for (int i = 0; i < 2; ++i) {
        const int c = tid + 256 * i;
        const int row = c >> 3, koff = (c & 7) << 3;
        const size_t boff = (size_t)(gn + row) * K + k0 + 64 + koff;
        rb[0][i] = *(const short8*)(Bthi + boff);
        rb[1][i] = *(const short8*)(Btlo + boff);
        const size_t aoff = (size_t)(bm + row) * K + k0 + 64 + koff;
        ra[0][i] = *(const short8*)(Ahi + aoff);
        ra[1][i] = *(const short8*)(Alo + aoff);
      }
    }
    asm volatile("s_waitcnt lgkmcnt(0)" ::: "memory");   // publish ds_writes (no vmcnt drain)
    __builtin_amdgcn_sched_barrier(0);
    __builtin_amdgcn_s_barrier();
    __builtin_amdgcn_sched_barrier(0);
#pragma unroll
    for (int kc = 0; kc < 2; ++kc) {
      const int ko = kc * 32 + q * 8;
      short8 aH[2], aL[2], bH[2], bL[2];
#pragma unroll
      for (int i = 0; i < 2; ++i) {
        aH[i] = *(const short8*)(&sA0[(wm + i * 16 + l15) * LSTR + ko]);
        aL[i] = *(const short8*)(&sA1[(wm + i * 16 + l15) * LSTR + ko]);
        bH[i] = *(const short8*)(&sB0[(wn + i * 16 + l15) * LSTR + ko]);
        bL[i] = *(const short8*)(&sB1[(wn + i * 16 + l15) * LSTR + ko]);
      }
#pragma unroll
      for (int i = 0; i < 2; ++i)
#pragma unroll
        for (int j = 0; j < 2; ++j) {
          acc[i][j] = __builtin_amdgcn_mfma_f32_16x16x32_bf16(aH[i], bH[j], acc[i][j], 0, 0, 0);
          acc[i][j] = __builtin_amdgcn_mfma_f32_16x16x32_bf16(aH[i], bL[j], acc[i][j], 0, 0, 0);
          acc[i][j] = __builtin_amdgcn_mfma_f32_16x16x32_bf16(aL[i], bH[j], acc[i][j], 0, 0, 0);
        }
    }
  }
  // epilogue: n = lane&15 (col), m = quad*4 + reg (row)
  const size_t headOff = (size_t)head * N;
  const int colh0 = bn + wn + l15;
  const int colh1 = colh0 + 16;
  const float bv0 = bias[head * N + colh0];
  const float bv1 = bias[head * N + colh1];
  float as0 = 0.f, as1 = 0.f, ad0 = 0.f, ad1 = 0.f;
  if (aptr) {
    as0 = aptr[head * 2 * N + colh0];
    as1 = aptr[head * 2 * N + colh1];
    ad0 = aptr[head * 2 * N + N + colh0];
    ad1 = aptr[head * 2 * N + N + colh1];
  }
#pragma unroll
  for (int i = 0; i < 2; ++i) {
    const int rowb = bm + wm + i * 16 + q * 4;
#pragma unroll
    for (int r = 0; r < 4; ++r) {
      const float o0 = acc[i][0][r] + bv0;
      const float o1 = acc[i][1][r] + bv1;
      if (Cb) {
        Cb[(size_t)(rowb + r) * rowStride + headOff + colh0] = bf16_rn(o0);
        Cb[(size_t)(rowb + r) * rowStride + headOff + colh1] = bf16_rn(o1);
      } else {
        C[(size_t)(rowb + r) * N + colh0] = o0;
        C[(size_t)(rowb + r) * N + colh1] = o1;
      }
      if (aptr) {  // wave-uniform; alpha/beta from fp32 acc (exact)
        float pa = o0 * as0 + o1 * as1;
        float pb = o0 * ad0 + o1 * ad1;
#pragma unroll
        for (int off = 1; off < 16; off <<= 1) {
          pa += __shfl_xor(pa, off, 64);
          pb += __shfl_xor(pb, off, 64);
        }
        if (l15 == 0) {
          atomicAdd(&alphaB[(size_t)(rowb + r) * Htot + head], pa);
          atomicAdd(&betaB[(size_t)(rowb + r) * Htot + head], pb);
        }
      }
    }
  }
}

// ---------------- fused 4-head attention + ELU + head-mean ----------------
// One wave per ROW, all HEADS heads at once. hB layout [Nn][HEADS][D] bf16; alpha/beta
// laid [Nn][HEADS] (one float4 per edge). xm = mean_h(ELU) in fp32, stored split-bf16.
__global__ __launch_bounds__(256) void attn4_kernel(
    const unsigned short* __restrict__ hB,
    const float* __restrict__ alpha, const float* __restrict__ beta,
    const float* __restrict__ ab, const int* __restrict__ cnt,
    const int* __restrict__ colb,
    unsigned short* __restrict__ oHi, unsigned short* __restrict__ oLo, int Nn) {
  const int tid = threadIdx.x;
  const int lane = tid & 63;
  const int wv = tid >> 6;
  const int i = blockIdx.x * 4 + wv;

  const unsigned short* hL = hB + (lane << 2);   // + (c*HEADS + h)*D per gather
  const float ai0 = alpha[i * HEADS + 0] + ab[0];
  const float ai1 = alpha[i * HEADS + 1] + ab[1];
  const float ai2 = alpha[i * HEADS + 2] + ab[2];
  const float ai3 = alpha[i * HEADS + 3] + ab[3];
  const int start = i * MAXB;
  int len = cnt[i];
  if (len > MAXB) len = MAXB;

  float m0 = -3.0e38f, m1 = -3.0e38f, m2 = -3.0e38f, m3 = -3.0e38f;
  float s0 = 0.f, s1 = 0.f, s2 = 0.f, s3 = 0.f;
  float4 A0 = make_float4(0.f, 0.f, 0.f, 0.f);
  float4 A1 = make_float4(0.f, 0.f, 0.f, 0.f);
  float4 A2 = make_float4(0.f, 0.f, 0.f, 0.f);
  float4 A3 = make_float4(0.f, 0.f, 0.f, 0.f);

  for (int t0 = 0; t0 < len; t0 += 64) {
    const int t = t0 + lane;
    const int c = (t < len) ? colb[start + t] : -1;
    float e0 = -3.0e38f, e1 = -3.0e38f, e2 = -3.0e38f, e3 = -3.0e38f;
    if (c >= 0) {
      const float4 b4 = *(const float4*)(beta + (size_t)c * HEADS);
      e0 = ai0 + b4.x; e1 = ai1 + b4.y; e2 = ai2 + b4.z; e3 = ai3 + b4.w;
      e0 = e0 > 0.0f ? e0 : NEG_SLOPE * e0;
      e1 = e1 > 0.0f ? e1 : NEG_SLOPE * e1;
      e2 = e2 > 0.0f ? e2 : NEG_SLOPE * e2;
      e3 = e3 > 0.0f ? e3 : NEG_SLOPE * e3;
    }
    float c0 = e0, c1 = e1, c2 = e2, c3 = e3;
#pragma unroll
    for (int off = 32; off > 0; off >>= 1) {
      c0 = fmaxf(c0, __shfl_xor(c0, off, 64));
      c1 = fmaxf(c1, __shfl_xor(c1, off, 64));
      c2 = fmaxf(c2, __shfl_xor(c2, off, 64));
      c3 = fmaxf(c3, __shfl_xor(c3, off, 64));
    }
    const float n0 = fmaxf(m0, c0), n1 = fmaxf(m1, c1);
    const float n2 = fmaxf(m2, c2), n3 = fmaxf(m3, c3);
    const float sc0 = __expf(m0 - n0), sc1 = __expf(m1 - n1);
    const float sc2 = __expf(m2 - n2), sc3 = __expf(m3 - n3);
    float w0 = 0.f, w1 = 0.f, w2 = 0.f, w3 = 0.f;
    if (c >= 0) {
      w0 = __expf(e0 - n0); w1 = __expf(e1 - n1);
      w2 = __expf(e2 - n2); w3 = __expf(e3 - n3);
    }
    float q0 = w0, q1 = w1, q2 = w2, q3 = w3;
#pragma unroll
    for (int off = 32; off > 0; off >>= 1) {
      q0 += __shfl_xor(q0, off, 64);
      q1 += __shfl_xor(q1, off, 64);
      q2 += __shfl_xor(q2, off, 64);
      q3 += __shfl_xor(q3, off, 64);
    }
    s0 = s0 * sc0 + q0; s1 = s1 * sc1 + q1;
    s2 = s2 * sc2 + q2; s3 = s3 * sc3 + q3;
    A0.x *= sc0; A0.y *= sc0; A0.z *= sc0; A0.w *= sc0;
    A1.x *= sc1; A1.y *= sc1; A1.z *= sc1; A1.w *= sc1;
    A2.x *= sc2; A2.y *= sc2; A2.z *= sc2; A2.w *= sc2;
    A3.x *= sc3; A3.y *= sc3; A3.z *= sc3; A3.w *= sc3;
    m0 = n0; m1 = n1; m2 = n2; m3 = n3;

    const int cS = (c >= 0) ? c : 0;
    const int cnt2 = min(64, len - t0);
    int j = 0;
    for (; j + 2 <= cnt2; j += 2) {
      const int ca = __shfl(cS, j);
      const int cb = __shfl(cS, j + 1);
      const float wa0 = __shfl(w0, j),     wa1 = __shfl(w1, j);
      const float wa2 = __shfl(w2, j),     wa3 = __shfl(w3, j);
      const float wb0 = __shfl(w0, j + 1), wb1 = __shfl(w1, j + 1);
      const float wb2 = __shfl(w2, j + 1), wb3 = __shfl(w3, j + 1);
      const unsigned short* pa = hL + (size_t)ca * (HEADS * D);
      const unsigned short* pb = hL + (size_t)cb * (HEADS * D);
      const ushort4 ua0 = *(const ushort4*)(pa);
      const ushort4 ua1 = *(const ushort4*)(pa + D);
      const ushort4 ua2 = *(const ushort4*)(pa + 2 * D);
      const ushort4 ua3 = *(const ushort4*)(pa + 3 * D);
      const ushort4 ub0 = *(const ushort4*)(pb);
      const ushort4 ub1 = *(const ushort4*)(pb + D);
      const ushort4 ub2 = *(const ushort4*)(pb + 2 * D);
      const ushort4 ub3 = *(const ushort4*)(pb + 3 * D);
      A0.x += wa0 * bf16_tof(ua0.x); A0.y += wa0 * bf16_tof(ua0.y);
      A0.z += wa0 * bf16_tof(ua0.z); A0.w += wa0 * bf16_tof(ua0.w);
      A1.x += wa1 * bf16_tof(ua1.x); A1.y += wa1 * bf16_tof(ua1.y);
      A1.z += wa1 * bf16_tof(ua1.z); A1.w += wa1 * bf16_tof(ua1.w);
      A2.x += wa2 * bf16_tof(ua2.x); A2.y += wa2 * bf16_tof(ua2.y);
      A2.z += wa2 * bf16_tof(ua2.z); A2.w += wa2 * bf16_tof(ua2.w);
      A3.x += wa3 * bf16_tof(ua3.x); A3.y += wa3 * bf16_tof(ua3.y);
      A3.z += wa3 * bf16_tof(ua3.z); A3.w += wa3 * bf16_tof(ua3.w);
      A0.x += wb0 * bf16_tof(ub0.x); A0.y += wb0 * bf16_tof(ub0.y);
      A0.z += wb0 * bf16_tof(ub0.z); A0.w += wb0 * bf16_tof(ub0.w);
      A1.x += wb1 * bf16_tof(ub1.x); A1.y += wb1 * bf16_tof(ub1.y);
      A1.z += wb1 * bf16_tof(ub1.z); A1.w += wb1 * bf16_tof(ub1.w);
      A2.x += wb2 * bf16_tof(ub2.x); A2.y += wb2 * bf16_tof(ub2.y);
      A2.z += wb2 * bf16_tof(ub2.z); A2.w += wb2 * bf16_tof(ub2.w);
      A3.x += wb3 * bf16_tof(ub3.x); A3.y += wb3 * bf16_tof(ub3.y);
      A3.z += wb3 * bf16_tof(ub3.z); A3.w += wb3 * bf16_tof(ub3.w);
    }
    for (; j < cnt2; ++j) {
      const int ca = __shfl(cS, j);
      const float wa0 = __shfl(w0, j), wa1 = __shfl(w1, j);
      const float wa2 = __shfl(w2, j), wa3 = __shfl(w3, j);
      const unsigned short* pa = hL + (size_t)ca * (HEADS * D);
      const ushort4 ua0 = *(const ushort4*)(pa);
      const ushort4 ua1 = *(const ushort4*)(pa + D);
      const ushort4 ua2 = *(const ushort4*)(pa + 2 * D);
      const ushort4 ua3 = *(const ushort4*)(pa + 3 * D);
      A0.x += wa0 * bf16_tof(ua0.x); A0.y += wa0 * bf16_tof(ua0.y);
      A0.z += wa0 * bf16_tof(ua0.z); A0.w += wa0 * bf16_tof(ua0.w);
      A1.x += wa1 * bf16_tof(ua1.x); A1.y += wa1 * bf16_tof(ua1.y);
      A1.z += wa1 * bf16_tof(ua1.z); A1.w += wa1 * bf16_tof(ua1.w);
      A2.x += wa2 * bf16_tof(ua2.x); A2.y += wa2 * bf16_tof(ua2.y);
      A2.z += wa2 * bf16_tof(ua2.z); A2.w += wa2 * bf16_tof(ua2.w);
      A3.x += wa3 * bf16_tof(ua3.x); A3.y += wa3 * bf16_tof(ua3.y);
      A3.z += wa3 * bf16_tof(ua3.z); A3.w += wa3 * bf16_tof(ua3.w);
    }
  }

  const float i0 = 1.0f / s0, i1 = 1.0f / s1, i2 = 1.0f / s2, i3 = 1.0f / s3;
  auto elu = [](float x) { return x > 0.0f ? x : expm1f(x); };
  float4 xm;
  xm.x = 0.25f * (elu(A0.x * i0) + elu(A1.x * i1) + elu(A2.x * i2) + elu(A3.x * i3));
  xm.y = 0.25f * (elu(A0.y * i0) + elu(A1.y * i1) + elu(A2.y * i2) + elu(A3.y * i3));
  xm.z = 0.25f * (elu(A0.z * i0) + elu(A1.z * i1) + elu(A2.z * i2) + elu(A3.z * i3));
  xm.w = 0.25f * (elu(A0.w * i0) + elu(A1.w * i1) + elu(A2.w * i2) + elu(A3.w * i3));
  ushort4 h4, l4;
  split2(xm.x, h4.x, l4.x);
  split2(xm.y, h4.y, l4.y);
  split2(xm.z, h4.z, l4.z);
  split2(xm.w, h4.w, l4.w);
  const size_t q4 = ((size_t)i * D >> 2) + lane;
  ((ushort4*)oHi)[q4] = h4;
  ((ushort4*)oLo)[q4] = l4;
}

// ---------------- single-head attention + ELU + lrelu + split-bf16 store ----------------
__global__ __launch_bounds__(256) void attn2m3_kernel(
    const unsigned short* __restrict__ hB,
    const float* __restrict__ alpha, const float* __restrict__ beta,
    const float* __restrict__ ab, const int* __restrict__ cnt,
    const int* __restrict__ colb,
    unsigned short* __restrict__ oHi, unsigned short* __restrict__ oLo, int Nn) {
  const int tid = threadIdx.x;
  const int lane = tid & 63;
  const int wv = tid >> 6;
  const int i = blockIdx.x * 4 + wv;
  const unsigned short* hLB = hB + (lane << 2);
  const float ai = alpha[i] + ab[0];
  const int start = i * MAXB;
  int len = cnt[i];
  if (len > MAXB) len = MAXB;

  float m = -3.0e38f, s = 0.0f;
  float4 acc0 = make_float4(0.0f, 0.0f, 0.0f, 0.0f);
  float4 acc1 = make_float4(0.0f, 0.0f, 0.0f, 0.0f);

  for (int t0 = 0; t0 < len; t0 += 64) {
    const int t = t0 + lane;
    const int c = (t < len) ? colb[start + t] : -1;
    float e = -3.0e38f;
    if (c >= 0) {
      e = ai + beta[c];
      e = e > 0.0f ? e : NEG_SLOPE * e;
    }
    float cm = e;
#pragma unroll
    for (int off = 32; off > 0; off >>= 1) cm = fmaxf(cm, __shfl_xor(cm, off, 64));
    const float newm = fmaxf(m, cm);
    const float scale = __expf(m - newm);
    const float w = (c >= 0) ? __expf(e - newm) : 0.0f;
    float cs = w;
#pragma unroll
    for (int off = 32; off > 0; off >>= 1) cs += __shfl_xor(cs, off, 64);
    s = s * scale + cs;
    acc0.x *= scale; acc0.y *= scale; acc0.z *= scale; acc0.w *= scale;
    acc1.x *= scale; acc1.y *= scale; acc1.z *= scale; acc1.w *= scale;
    m = newm;

    const int cS = (c >= 0) ? c : 0;
    const int cnt2 = min(64, len - t0);
    int j = 0;
    for (; j + 4 <= cnt2; j += 4) {
      const int c0 = __shfl(cS, j);     const float w0 = __shfl(w, j);
      const int c1 = __shfl(cS, j + 1); const float w1 = __shfl(w, j + 1);
      const int c2 = __shfl(cS, j + 2); const float w2 = __shfl(w, j + 2);
      const int c3 = __shfl(cS, j + 3); const float w3 = __shfl(w, j + 3);
      const ushort4 u0 = *(const ushort4*)(hLB + (size_t)c0 * D);
      const ushort4 u1 = *(const ushort4*)(hLB + (size_t)c1 * D);
      const ushort4 u2 = *(const ushort4*)(hLB + (size_t)c2 * D);
      const ushort4 u3 = *(const ushort4*)(hLB + (size_t)c3 * D);
      acc0.x += w0 * bf16_tof(u0.x); acc0.y += w0 * bf16_tof(u0.y);
      acc0.z += w0 * bf16_tof(u0.z); acc0.w += w0 * bf16_tof(u0.w);
      acc1.x += w1 * bf16_tof(u1.x); acc1.y += w1 * bf16_tof(u1.y);
      acc1.z += w1 * bf16_tof(u1.z); acc1.w += w1 * bf16_tof(u1.w);
      acc0.x += w2 * bf16_tof(u2.x); acc0.y += w2 * bf16_tof(u2.y);
      acc0.z += w2 * bf16_tof(u2.z); acc0.w += w2 * bf16_tof(u2.w);
      acc1.x += w3 * bf16_tof(u3.x); acc1.y += w3 * bf16_tof(u3.y);
      acc1.z += w3 * bf16_tof(u3.z); acc1.w += w3 * bf16_tof(u3.w);
    }
    for (; j < cnt2; ++j) {
      const int cj = __shfl(cS, j);
      const float wj = __shfl(w, j);
      const ushort4 uu = *(const ushort4*)(hLB + (size_t)cj * D);
      acc0.x += wj * bf16_tof(uu.x); acc0.y += wj * bf16_tof(uu.y);
      acc0.z += wj * bf16_tof(uu.z); acc0.w += wj * bf16_tof(uu.w);
    }
  }

  const float inv = 1.0f / s;
  float4 v;
  v.x = (acc0.x + acc1.x) * inv; v.y = (acc0.y + acc1.y) * inv;
  v.z = (acc0.z + acc1.z) * inv; v.w = (acc0.w + acc1.w) * inv;
  v.x = v.x > 0.0f ? v.x : expm1f(v.x);
  v.y = v.y > 0.0f ? v.y : expm1f(v.y);
  v.z = v.z > 0.0f ? v.z : expm1f(v.z);
  v.w = v.w > 0.0f ? v.w : expm1f(v.w);
  v.x = v.x > 0.0f ? v.x : NEG_SLOPE * v.x;
  v.y = v.y > 0.0f ? v.y : NEG_SLOPE * v.y;
  v.z = v.z > 0.0f ? v.z : NEG_SLOPE * v.z;
  v.w = v.w > 0.0f ? v.w : NEG_SLOPE * v.w;
  ushort4 h4, l4;
  split2(v.x, h4.x, l4.x);
  split2(v.y, h4.y, l4.y);
  split2(v.z, h4.z, l4.z);
  split2(v.w, h4.w, l4.w);
  const size_t q4 = ((size_t)i * D >> 2) + lane;
  ((ushort4*)oHi)[q4] = h4;
  ((ushort4*)oLo)[q4] = l4;
}

// =================== fp32 fallback-path kernels (small-ws only) ===================
__global__ __launch_bounds__(256) void gemm_bias(
    const float* __restrict__ A, const float* __restrict__ B,
    const float* __restrict__ bias, float* __restrict__ C,
    int M, int N, int K) {
  __shared__ float As[16][68];
  __shared__ float Bs[16][68];
  const int tid = threadIdx.x;
  const int bm = blockIdx.x * 64;
  const int gn = blockIdx.y * 64;
  const int head = gn / N;
  const int bn = gn - head * N;
  const float* Bh = B + (size_t)head * K * N;
  const int tx = tid & 15;
  const int ty = tid >> 4;
  const int am = tid >> 2;
  const int ak = (tid & 3) << 2;
  const int bk = tid >> 4;
  const int bn4 = (tid & 15) << 2;
  float acc[4][4] = {};
  for (int k0 = 0; k0 < K; k0 += 16) {
    float4 av = *(const float4*)(A + (size_t)(bm + am) * K + (k0 + ak));
    float4 bv = *(const float4*)(Bh + (size_t)(k0 + bk) * N + (bn + bn4));
    __syncthreads();
    As[ak + 0][am] = av.x;
    As[ak + 1][am] = av.y;
    As[ak + 2][am] = av.z;
    As[ak + 3][am] = av.w;
    *(float4*)(&Bs[bk][bn4]) = bv;
    __syncthreads();
#pragma unroll
    for (int k = 0; k < 16; ++k) {
      float4 aa = *(const float4*)(&As[k][ty << 2]);
      float4 bb = *(const float4*)(&Bs[k][tx << 2]);
      acc[0][0] += aa.x * bb.x; acc[0][1] += aa.x * bb.y; acc[0][2] += aa.x * bb.z; acc[0][3] += aa.x * bb.w;
      acc[1][0] += aa.y * bb.x; acc[1][1] += aa.y * bb.y; acc[1][2] += aa.y * bb.z; acc[1][3] += aa.y * bb.w;
      acc[2][0] += aa.z * bb.x; acc[2][1] += aa.z * bb.y; acc[2][2] += aa.z * bb.z; acc[2][3] += aa.z * bb.w;
      acc[3][0] += aa.w * bb.x; acc[3][1] += aa.w * bb.y; acc[3][2] += aa.w * bb.z; acc[3][3] += aa.w * bb.w;
    }
  }
  float* Ch = C + (size_t)head * M * N;
  const float* bh = bias + (size_t)head * N;
  const int ccol = bn + (tx << 2);
  float4 bias4 = *(const float4*)(bh + ccol);
#pragma unroll
  for (int r = 0; r < 4; ++r) {
    int row = bm + (ty << 2) + r;
    float4 o;
    o.x = acc[r][0] + bias4.x;
    o.y = acc[r][1] + bias4.y;
    o.z = acc[r][2] + bias4.z;
    o.w = acc[r][3] + bias4.w;
    *(float4*)(Ch + (size_t)row * N + ccol) = o;
  }
}

__global__ __launch_bounds__(256) void alphabeta_kernel(
    const float* __restrict__ h, const float* __restrict__ a,
    float* __restrict__ alpha, float* __restrict__ beta, int Nn) {
  __shared__ float reda[4], redb[4];
  const int i = blockIdx.x;
  const int hh = blockIdx.y;
  const int tid = threadIdx.x;
  const int lane = tid & 63, wid = tid >> 6;
  float v = h[((size_t)hh * Nn + i) * D + tid];
  float pa = v * a[hh * 2 * D + tid];
  float pb = v * a[hh * 2 * D + D + tid];
#pragma unroll
  for (int off = 32; off > 0; off >>= 1) {
    pa += __shfl_xor(pa, off, 64);
    pb += __shfl_xor(pb, off, 64);
  }
  if (lane == 0) { reda[wid] = pa; redb[wid] = pb; }
  __syncthreads();
  if (tid == 0) {
    alpha[hh * Nn + i] = reda[0] + reda[1] + reda[2] + reda[3];
    beta[hh * Nn + i] = redb[0] + redb[1] + redb[2] + redb[3];
  }
}

__global__ __launch_bounds__(256) void attn2f(
    const float* __restrict__ h,
    const float* __restrict__ alpha, const float* __restrict__ beta,
    const float* __restrict__ ab, const int* __restrict__ cnt,
    const int* __restrict__ colb, float* __restrict__ out,
    int Nn, int H, int mode) {
  const int tid = threadIdx.x;
  const int lane = tid & 63;
  const int wv = tid >> 6;
  const int bx = blockIdx.x;
  const int head = bx % H;
  const int rowblk = bx / H;
  const int i = rowblk * 4 + wv;

  const float* hL = h + (size_t)head * Nn * D + (lane << 2);
  const float* betaH = beta + (size_t)head * Nn;
  const float ai = alpha[head * Nn + i] + ab[head];
  const int start = i * MAXB;
  int len = cnt[i];
  if (len > MAXB) len = MAXB;

  float m = -3.0e38f, s = 0.0f;
  float4 acc0 = make_float4(0.0f, 0.0f, 0.0f, 0.0f);
  float4 acc1 = make_float4(0.0f, 0.0f, 0.0f, 0.0f);

  for (int t0 = 0; t0 < len; t0 += 64) {
    const int t = t0 + lane;
    const int c = (t < len) ? colb[start + t] : -1;
    float e = -3.0e38f;
    if (c >= 0) {
      e = ai + betaH[c];
      e = e > 0.0f ? e : NEG_SLOPE * e;
    }
    float cm = e;
#pragma unroll
    for (int off = 32; off > 0; off >>= 1) cm = fmaxf(cm, __shfl_xor(cm, off, 64));
    const float newm = fmaxf(m, cm);
    const float scale = __expf(m - newm);
    const float w = (c >= 0) ? __expf(e - newm) : 0.0f;
    float cs = w;
#pragma unroll
    for (int off = 32; off > 0; off >>= 1) cs += __shfl_xor(cs, off, 64);
    s = s * scale + cs;
    acc0.x *= scale; acc0.y *= scale; acc0.z *= scale; acc0.w *= scale;
    acc1.x *= scale; acc1.y *= scale; acc1.z *= scale; acc1.w *= scale;
    m = newm;

    const int cS = (c >= 0) ? c : 0;
    const int cnt2 = min(64, len - t0);
    int j = 0;
    for (; j + 4 <= cnt2; j += 4) {
      const int c0 = __shfl(cS, j);     const float w0 = __shfl(w, j);
      const int c1 = __shfl(cS, j + 1); const float w1 = __shfl(w, j + 1);
      const int c2 = __shfl(cS, j + 2); const float w2 = __shfl(w, j + 2);
      const int c3 = __shfl(cS, j + 3); const float w3 = __shfl(w, j + 3);
      const float4 h0 = *(const float4*)(hL + (size_t)c0 * D);
      const float4 h1 = *(const float4*)(hL + (size_t)c1 * D);
      const float4 h2 = *(const float4*)(hL + (size_t)c2 * D);
      const float4 h3 = *(const float4*)(hL + (size_t)c3 * D);
      acc0.x += w0 * h0.x; acc0.y += w0 * h0.y; acc0.z += w0 * h0.z; acc0.w += w0 * h0.w;
      acc1.x += w1 * h1.x; acc1.y += w1 * h1.y; acc1.z += w1 * h1.z; acc1.w += w1 * h1.w;
      acc0.x += w2 * h2.x; acc0.y += w2 * h2.y; acc0.z += w2 * h2.z; acc0.w += w2 * h2.w;
      acc1.x += w3 * h3.x; acc1.y += w3 * h3.y; acc1.z += w3 * h3.z; acc1.w += w3 * h3.w;
    }
    for (; j < cnt2; ++j) {
      const int cj = __shfl(cS, j);
      const float wj = __shfl(w, j);
      const float4 hv = *(const float4*)(hL + (size_t)cj * D);
      acc0.x += wj * hv.x; acc0.y += wj * hv.y;
      acc0.z += wj * hv.z; acc0.w += wj * hv.w;
    }
  }

  const float inv = 1.0f / s;
  float4 v;
  v.x = (acc0.x + acc1.x) * inv; v.y = (acc0.y + acc1.y) * inv;
  v.z = (acc0.z + acc1.z) * inv; v.w = (acc0.w + acc1.w) * inv;
  v.x = v.x > 0.0f ? v.x : expm1f(v.x);
  v.y = v.y > 0.0f ? v.y : expm1f(v.y);
  v.z = v.z > 0.0f ? v.z : expm1f(v.z);
  v.w = v.w > 0.0f ? v.w : expm1f(v.w);

  if (mode == 1) {
    v.x = v.x > 0.0f ? v.x : NEG_SLOPE * v.x;
    v.y = v.y > 0.0f ? v.y : NEG_SLOPE * v.y;
    v.z = v.z > 0.0f ? v.z : NEG_SLOPE * v.z;
    v.w = v.w > 0.0f ? v.w : NEG_SLOPE * v.w;
    *(float4*)(out + (size_t)i * D + (lane << 2)) = v;
  } else if (mode == 0) {
    *(float4*)(out + ((size_t)head * Nn + i) * D + (lane << 2)) = v;
  } else {
    const float invH = 1.0f / (float)H;
    float* o = out + (size_t)i * D + (lane << 2);
    atomicAdd(o + 0, invH * v.x);
    atomicAdd(o + 1, invH * v.y);
    atomicAdd(o + 2, invH * v.z);
    atomicAdd(o + 3, invH * v.w);
  }
}

__global__ __launch_bounds__(256) void mean4_kernel(float* __restrict__ hsep, int total4) {
  int idx = blockIdx.x * blockDim.x + threadIdx.x;
  if (idx < total4) {
    float4* p = (float4*)hsep;
    float4 a = p[idx], b = p[idx + total4], c = p[idx + 2 * total4], d = p[idx + 3 * total4];
    float4 o;
    o.x = 0.25f * (a.x + b.x + c.x + d.x);
    o.y = 0.25f * (a.y + b.y + c.y + d.y);
    o.z = 0.25f * (a.z + b.z + c.z + d.z);
    o.w = 0.25f * (a.w + b.w + c.w + d.w);
    p[idx] = o;
  }
}

__global__ void zero_ints(int* __restrict__ p, int n) {
  int i = blockIdx.x * blockDim.x + threadIdx.x;
  if (i < n) p[i] = 0;
}

__global__ void zero_floats(float* __restrict__ p, int n) {
  int i = blockIdx.x * blockDim.x + threadIdx.x;
  if (i < n) p[i] = 0.0f;
}

// ---------------- host ----------------
extern "C" void kernel_launch(void* const* d_in, const int* in_sizes, int n_in,
                              void* d_out, int out_size, void* d_ws, size_t ws_size,
                              hipStream_t stream) {
  const float* x = (const float*)d_in[0];
  const int* eidx = (const int*)d_in[1];
  const float* l0_hW = (const float*)d_in[2];
  const float* l0_hWb = (const float*)d_in[3];
  const float* l0_ha = (const float*)d_in[4];
  const float* l0_hab = (const float*)d_in[5];
  const float* l0_oW = (const float*)d_in[6];
  const float* l0_oWb = (const float*)d_in[7];
  const float* l0_oa = (const float*)d_in[8];
  const float* l0_oab = (const float*)d_in[9];
  const float* l1_hW = (const float*)d_in[10];
  const float* l1_hWb = (const float*)d_in[11];
  const float* l1_ha = (const float*)d_in[12];
  const float* l1_hab = (const float*)d_in[13];
  const float* l1_oW = (const float*)d_in[14];
  const float* l1_oWb = (const float*)d_in[15];
  const float* l1_oa = (const float*)d_in[16];
  const float* l1_oab = (const float*)d_in[17];
  const float* lin_W = (const float*)d_in[18];
  const float* lin_b = (const float*)d_in[19];

  const int in_dim = 512;
  const int Nn = in_sizes[0] / in_dim;  // 4096
  const int E = in_sizes[1] / 2;        // 131072
  const int out_dim = 128;

  char* wsp = (char*)d_ws;
  auto alloc = [&](size_t bytes) {
    char* p = wsp;
    wsp += (bytes + 255) & ~(size_t)255;
    return p;
  };
  const size_t ndBytes = sizeof(float) * (size_t)Nn * D;        // 4 MB
  const size_t mfmaNeed = 52000000;
  const bool mfma = ws_size >= mfmaNeed;

  if (mfma) {
    unsigned short* hbufB = (unsigned short*)alloc((size_t)HEADS * Nn * D * 2); // [row][head][D] bf16
    unsigned short* houtB = (unsigned short*)alloc((size_t)Nn * D * 2);
    unsigned short* xmHi  = (unsigned short*)alloc((size_t)Nn * D * 2);
    unsigned short* xmLo  = (unsigned short*)alloc((size_t)Nn * D * 2);
    unsigned short* xhi  = (unsigned short*)alloc((size_t)Nn * in_dim * 2);
    unsigned short* xlo  = (unsigned short*)alloc((size_t)Nn * in_dim * 2);
    unsigned short* x1hi = xhi;                                  // alias: x dead after L0 head gemm
    unsigned short* x1lo = xlo;
    unsigned short* l0hHi = (unsigned short*)alloc((size_t)HEADS * in_dim * D * 2);
    unsigned short* l0hLo = (unsigned short*)alloc((size_t)HEADS * in_dim * D * 2);
    unsigned short* l1hHi = (unsigned short*)alloc((size_t)HEADS * D * D * 2);
    unsigned short* l1hLo = (unsigned short*)alloc((size_t)HEADS * D * D * 2);
    unsigned short* l0oHi = (unsigned short*)alloc((size_t)D * D * 2);
    unsigned short* l0oLo = (unsigned short*)alloc((size_t)D * D * 2);
    unsigned short* l1oHi = (unsigned short*)alloc((size_t)D * D * 2);
    unsigned short* l1oLo = (unsigned short*)alloc((size_t)D * D * 2);
    unsigned short* linHi = (unsigned short*)alloc((size_t)D * out_dim * 2);
    unsigned short* linLo = (unsigned short*)alloc((size_t)D * out_dim * 2);
    int* cnt     = (int*)alloc(sizeof(int) * Nn);
    float* abz   = (float*)alloc(sizeof(float) * 4 * 2 * HEADS * (size_t)Nn);
    int* colb    = (int*)alloc(sizeof(int) * (size_t)Nn * MAXB);
    auto alphaS = [&](int s) { return abz + (size_t)s * 2 * HEADS * Nn; };
    auto betaS  = [&](int s) { return abz + (size_t)s * 2 * HEADS * Nn + HEADS * Nn; };

    const int* src = eidx;
    const int* dst = eidx + E;
    const int zeroN = Nn + 4 * 2 * HEADS * Nn;   // 135168
    const int tilesX = Nn / 64;

    // prep: zero cnt+abz, split x, transpose+split all weights (ONE dispatch)
    prep_kernel<<<3536, 256, 0, stream>>>(
        cnt, zeroN, x, xhi, xlo, Nn * in_dim / 4,
        l0_hW, l0hHi, l0hLo, l1_hW, l1hHi, l1hLo,
        l0_oW, l0oHi, l0oLo, l1_oW, l1oHi, l1oLo, lin_W, linHi, linLo);
    fill_kernel<<<(E + 255) / 256, 256, 0, stream>>>(src, dst, cnt, colb, E);
    dedupe2_kernel<<<Nn / 2, 256, 0, stream>>>(cnt, colb, Nn);

    // --- layer 0 ---
    gemm_k<<<tilesX * 16, 256, 0, stream>>>(xhi, xlo, l0hHi, l0hLo, l0_hWb, nullptr, hbufB,
                                            l0_ha, alphaS(0), betaS(0), 256, 512, 4, tilesX);
    attn4_kernel<<<Nn / 4, 256, 0, stream>>>(hbufB, alphaS(0), betaS(0), l0_hab, cnt, colb, xmHi, xmLo, Nn);
    gemm_k<<<tilesX * 4, 256, 0, stream>>>(xmHi, xmLo, l0oHi, l0oLo, l0_oWb, nullptr, houtB,
                                           l0_oa, alphaS(1), betaS(1), 256, 256, 1, tilesX);
    attn2m3_kernel<<<Nn / 4, 256, 0, stream>>>(houtB, alphaS(1), betaS(1), l0_oab, cnt, colb, x1hi, x1lo, Nn);

    // --- layer 1 ---
    gemm_k<<<tilesX * 16, 256, 0, stream>>>(x1hi, x1lo, l1hHi, l1hLo, l1_hWb, nullptr, hbufB,
                                            l1_ha, alphaS(2), betaS(2), 256, 256, 4, tilesX);
    attn4_kernel<<<Nn / 4, 256, 0, stream>>>(hbufB, alphaS(2), betaS(2), l1_hab, cnt, colb, xmHi, xmLo, Nn);
    gemm_k<<<tilesX * 4, 256, 0, stream>>>(xmHi, xmLo, l1oHi, l1oLo, l1_oWb, nullptr, houtB,
                                           l1_oa, alphaS(3), betaS(3), 256, 256, 1, tilesX);
    attn2m3_kernel<<<Nn / 4, 256, 0, stream>>>(houtB, alphaS(3), betaS(3), l1_oab, cnt, colb, x1hi, x1lo, Nn);

    // --- final linear (fp32 out, no alphabeta fusion) ---
    gemm_k<<<tilesX * 2, 256, 0, stream>>>(x1hi, x1lo, linHi, linLo, lin_b, (float*)d_out, nullptr,
                                           nullptr, nullptr, nullptr, 128, 256, 1, tilesX);
    return;
  }

  // ================= fallback: fp32 path (bucketed CSR) =================
  const size_t smallBytes = sizeof(float) * 2 * HEADS * (size_t)Nn + sizeof(int) * (Nn + (size_t)Nn * MAXB) + 4096;
  const bool staged = ws_size >= (8 * ndBytes + 2 * ndBytes + smallBytes + 65536);

  float* hbuf  = (float*)alloc(ndBytes * HEADS);
  float* hsep  = staged ? (float*)alloc(ndBytes * HEADS) : nullptr;
  float* xm    = staged ? hsep : (float*)alloc(ndBytes);
  float* x1    = (float*)alloc(ndBytes);
  float* hout  = (float*)alloc(ndBytes);
  float* alpha = (float*)alloc(sizeof(float) * HEADS * (size_t)Nn);
  float* beta  = (float*)alloc(sizeof(float) * HEADS * (size_t)Nn);
  int* cnt     = (int*)alloc(sizeof(int) * Nn);
  int* colb    = (int*)alloc(sizeof(int) * (size_t)Nn * MAXB);

  const int* src = eidx;
  const int* dst = eidx + E;

  zero_ints<<<(Nn + 255) / 256, 256, 0, stream>>>(cnt, Nn);
  fill_kernel<<<(E + 255) / 256, 256, 0, stream>>>(src, dst, cnt, colb, E);
  dedupe2_kernel<<<Nn / 2, 256, 0, stream>>>(cnt, colb, Nn);

  const int total4 = Nn * D / 4;
  const int meanBlocks = (total4 + 255) / 256;

  gemm_bias<<<dim3(Nn / 64, HEADS * D / 64), 256, 0, stream>>>(x, l0_hW, l0_hWb, hbuf, Nn, D, in_dim);
  alphabeta_kernel<<<dim3(Nn, HEADS), 256, 0, stream>>>(hbuf, l0_ha, alpha, beta, Nn);
  if (staged) {
    attn2f<<<HEADS * (Nn / 4), 256, 0, stream>>>(hbuf, alpha, beta, l0_hab, cnt, colb, hsep, Nn, HEADS, 0);
    mean4_kernel<<<meanBlocks, 256, 0, stream>>>(hsep, total4);
  } else {
    zero_floats<<<(Nn * D + 255) / 256, 256, 0, stream>>>(xm, Nn * D);
    attn2f<<<HEADS * (Nn / 4), 256, 0, stream>>>(hbuf, alpha, beta, l0_hab, cnt, colb, xm, Nn, HEADS, 2);
  }
  gemm_bias<<<dim3(Nn / 64, D / 64), 256, 0, stream>>>(xm, l0_oW, l0_oWb, hout, Nn, D, D);
  alphabeta_kernel<<<dim3(Nn, 1), 256, 0, stream>>>(hout, l0_oa, alpha, beta, Nn);
  attn2f<<<Nn / 4, 256, 0, stream>>>(hout, alpha, beta, l0_oab, cnt, colb, x1, Nn, 1, 1);

  gemm_bias<<<dim3(Nn / 64, HEADS * D / 64), 256, 0, stream>>>(x1, l1_hW, l1_hWb, hbuf, Nn, D, D);
  alphabeta_kernel<<<dim3(Nn, HEADS), 256, 0, stream>>>(hbuf, l1_ha, alpha, beta, Nn);
  if (staged) {
    attn2f<<<HEADS * (Nn / 4), 256, 0, stream>>>(hbuf, alpha, beta, l1_hab, cnt, colb, hsep, Nn, HEADS, 0);
    mean4_kernel<<<meanBlocks, 256, 0, stream>>>(hsep, total4);
  } else {
    zero_floats<<<(Nn * D + 255) / 256, 256, 0, stream>>>(xm, Nn * D);
    attn2f<<<HEADS * (Nn / 4), 256, 0, stream>>>(hbuf, alpha, beta, l1_hab, cnt, colb, xm, Nn, HEADS, 2);
  }
  gemm_bias<<<dim3(Nn / 64, D / 64), 256, 0, stream>>>(xm, l1_oW, l1_oWb, hout, Nn, D, D);
  alphabeta_kernel<<<dim3(Nn, 1), 256, 0, stream>>>(hout, l1_oa, alpha, beta, Nn);
  attn2f<<<Nn / 4, 256, 0, stream>>>(hout, alpha, beta, l1_oab, cnt, colb, x1, Nn, 1, 1);

  gemm_bias<<<dim3(Nn / 64, out_dim / 64), 256, 0, stream>>>(x1, lin_W, lin_b, (float*)d_out, Nn, out_dim, D);
}